// Round 8
// baseline (631.200 us; speedup 1.0000x reference)
//
#include <hip/hip_runtime.h>

typedef unsigned int uint;
typedef unsigned short ushort;

#define AB_U 132  // A/B row stride in uints (264 bf16 elems, 257 used)

__device__ __forceinline__ ushort f2bf(float f) {
    uint u = __float_as_uint(f);
    u += 0x7FFFu + ((u >> 16) & 1u);   // round-to-nearest-even
    return (ushort)(u >> 16);
}
__device__ __forceinline__ float bf2f_lo(uint p) { return __uint_as_float(p << 16); }
__device__ __forceinline__ float bf2f_hi(uint p) { return __uint_as_float(p & 0xFFFF0000u); }
__device__ __forceinline__ uint packbf(float lo, float hi) {
    return (uint)f2bf(lo) | ((uint)f2bf(hi) << 16);
}

// ---------------- precompute: temb MLP + rank-2 edge-lin factors ----------------
// wsmall layout (floats): temb[0:128] P2[128:256] Q2[256:384] R2[384:512]
//                         P3[512:640] Q3[640:768] R3[768:896] scal[896:899]
__global__ __launch_bounds__(256) void precompute_kernel(
    const float* __restrict__ t,
    const float* __restrict__ We, const float* __restrict__ be,
    const float* __restrict__ Wo, const float* __restrict__ bo,
    const float* __restrict__ Wl1, const float* __restrict__ bl1,
    const float* __restrict__ Wl2, const float* __restrict__ bl2,
    const float* __restrict__ Wl3, const float* __restrict__ bl3,
    const float* __restrict__ Wt1, const float* __restrict__ bt1,
    const float* __restrict__ Wt2, const float* __restrict__ bt2,
    float* __restrict__ wsmall)
{
    __shared__ float t0[128];
    __shared__ float y1[256];
    int tid = threadIdx.x;
    float tt = t[0] * 4.0f;
    if (tid < 64) {
        float f = expf(-logf(10000.0f) * (float)tid / 63.0f);
        float v = tt * f;
        t0[tid]      = sinf(v);
        t0[tid + 64] = cosf(v);
    }
    __syncthreads();
    {
        float acc = bt1[tid];
        for (int k = 0; k < 128; k++) acc = fmaf(t0[k], Wt1[k * 256 + tid], acc);
        y1[tid] = fmaxf(acc, 0.0f);
    }
    __syncthreads();
    if (tid < 128) {
        float a = bt2[tid];
        for (int k = 0; k < 256; k++) a = fmaf(y1[k], Wt2[k * 128 + tid], a);
        wsmall[tid] = a;  // temb
    }
    {
        int j = tid & 127;
        const float* Wl  = (tid < 128) ? Wl2 : Wl3;
        const float* blp = (tid < 128) ? bl2 : bl3;
        float p = 0.f, q = 0.f, r = blp[j];
        for (int k = 0; k < 64; k++) {
            float w1 = Wl[k * 128 + j], w2 = Wl[(64 + k) * 128 + j];
            p = fmaf(We[k], w1, p);
            q = fmaf(Wo[k], w2, q);
            r = fmaf(be[k], w1, r);
            r = fmaf(bo[k], w2, r);
        }
        int base = (tid < 128) ? 128 : 512;
        wsmall[base + j]       = p;
        wsmall[base + 128 + j] = q;
        wsmall[base + 256 + j] = r;
    }
    if (tid == 0) {
        float p1 = 0.f, q1 = 0.f, r1 = bl1[0];
        for (int k = 0; k < 64; k++) {
            p1 = fmaf(We[k], Wl1[k], p1);
            q1 = fmaf(Wo[k], Wl1[64 + k], q1);
            r1 = fmaf(be[k], Wl1[k], r1);
            r1 = fmaf(bo[k], Wl1[64 + k], r1);
        }
        wsmall[896] = p1; wsmall[897] = q1; wsmall[898] = r1;
    }
}

// stage Wd1[0:256][0:257] into Wp with 16B-aligned stride 260
__global__ __launch_bounds__(256) void wp_kernel(
    const float* __restrict__ Wd1, float* __restrict__ Wp)
{
    int k = blockIdx.x, o = threadIdx.x;
    Wp[k * 260 + o] = Wd1[k * 257 + o];
    if (o == 0) Wp[k * 260 + 256] = Wd1[k * 257 + 256];
}

// ---------------- CSR build: histogram -> hierarchical scan -> scatter ----------------
__global__ __launch_bounds__(256) void hist_kernel(
    const int* __restrict__ dst, int* __restrict__ cnt, int E)
{
    int e = blockIdx.x * blockDim.x + threadIdx.x;
    if (e < E) atomicAdd(&cnt[dst[e]], 1);
}

// per-block (1024 elems) exclusive scan; block total -> partials[b]
__global__ __launch_bounds__(256) void scan1_kernel(
    const int* __restrict__ cnt, int* __restrict__ rowstart,
    int* __restrict__ partials, int N)
{
    __shared__ int wsum[4];
    int b = blockIdx.x;
    int tid = threadIdx.x, lane = tid & 63, w = tid >> 6;
    int i0 = b * 1024 + tid * 4;
    int v0 = (i0     < N) ? cnt[i0]     : 0;
    int v1 = (i0 + 1 < N) ? cnt[i0 + 1] : 0;
    int v2 = (i0 + 2 < N) ? cnt[i0 + 2] : 0;
    int v3 = (i0 + 3 < N) ? cnt[i0 + 3] : 0;
    int tsum = v0 + v1 + v2 + v3;
    int s = tsum;
#pragma unroll
    for (int off = 1; off < 64; off <<= 1) {
        int u = __shfl_up(s, off, 64);
        if (lane >= off) s += u;
    }
    if (lane == 63) wsum[w] = s;
    __syncthreads();
    int woff = 0;
    for (int k = 0; k < w; k++) woff += wsum[k];
    int ex = woff + s - tsum;
    if (i0     < N) rowstart[i0]     = ex;
    if (i0 + 1 < N) rowstart[i0 + 1] = ex + v0;
    if (i0 + 2 < N) rowstart[i0 + 2] = ex + v0 + v1;
    if (i0 + 3 < N) rowstart[i0 + 3] = ex + v0 + v1 + v2;
    if (tid == 255) partials[b] = woff + s;
}

// single wave: exclusive scan of partials; also writes rowstart[N] = total
__global__ __launch_bounds__(64) void scan2_kernel(
    int* __restrict__ partials, int* __restrict__ rowstart, int nblk, int N)
{
    int lane = threadIdx.x;
    int carry = 0;
    for (int base = 0; base < nblk; base += 64) {
        int i = base + lane;
        int v = (i < nblk) ? partials[i] : 0;
        int s = v;
#pragma unroll
        for (int off = 1; off < 64; off <<= 1) {
            int u = __shfl_up(s, off, 64);
            if (lane >= off) s += u;
        }
        if (i < nblk) partials[i] = carry + s - v;
        carry += __shfl(s, 63, 64);
    }
    if (lane == 0) rowstart[N] = carry;
}

__global__ __launch_bounds__(256) void scan3_kernel(
    int* __restrict__ rowstart, const int* __restrict__ partials, int N)
{
    int i = blockIdx.x * blockDim.x + threadIdx.x;
    if (i < N) rowstart[i] += partials[i >> 10];
}

// scatter: build dst-grouped edge payload {e, src, ea, qy}
__global__ __launch_bounds__(256) void scatter_kernel(
    const int* __restrict__ src, const int* __restrict__ dst,
    const float* __restrict__ ea, const float* __restrict__ qy,
    const int* __restrict__ rowstart, int* __restrict__ cursor,
    uint4* __restrict__ epack, int E)
{
    int e = blockIdx.x * blockDim.x + threadIdx.x;
    if (e >= E) return;
    int d = dst[e];
    int pos = atomicAdd(&cursor[d], 1);
    uint4 pk;
    pk.x = (uint)e;
    pk.y = (uint)src[e];
    pk.z = __float_as_uint(ea[e]);
    pk.w = __float_as_uint(qy[e]);
    epack[rowstart[d] + pos] = pk;
}

// ---------------- layer 1 (scalar channel), pull over CSR, unroll 2 ----------------
__global__ __launch_bounds__(256) void edge1_kernel(
    const float* __restrict__ x, const uint4* __restrict__ epack,
    const int* __restrict__ rowstart, const float* __restrict__ scal,
    float* __restrict__ agg1, int N)
{
    int v = blockIdx.x * blockDim.x + threadIdx.x;
    if (v >= N) return;
    float s0 = scal[0], s1 = scal[1], s2 = scal[2];
    int beg = rowstart[v], end = rowstart[v + 1];
    float m = 0.0f;
    int i = beg;
    for (; i + 2 <= end; i += 2) {
        uint4 pk0 = epack[i];
        uint4 pk1 = epack[i + 1];
        float x0 = x[(int)pk0.y];
        float x1 = x[(int)pk1.y];
        m += fmaxf(x0 + fmaf(__uint_as_float(pk0.z), s0, fmaf(__uint_as_float(pk0.w), s1, s2)), 0.0f);
        m += fmaxf(x1 + fmaf(__uint_as_float(pk1.z), s0, fmaf(__uint_as_float(pk1.w), s1, s2)), 0.0f);
    }
    if (i < end) {
        uint4 pk = epack[i];
        m += fmaxf(x[(int)pk.y] + fmaf(__uint_as_float(pk.z), s0, fmaf(__uint_as_float(pk.w), s1, s2)), 0.0f);
    }
    agg1[v] = m;
}

// h1 = (x+agg1)*Wn1 + bn1 + temb ; also bf16 shadow
__global__ __launch_bounds__(256) void node1_kernel(
    const float* __restrict__ x, const float* __restrict__ agg1,
    const float* __restrict__ Wn1, const float* __restrict__ bn1,
    const float* __restrict__ temb, float* __restrict__ h,
    uint* __restrict__ h16u, int N)
{
    int i = blockIdx.x * blockDim.x + threadIdx.x;  // N*64 threads
    int n = i >> 6, j2 = (i & 63) * 2;
    if (n >= N) return;
    float v = x[n] + agg1[n];
    float h0 = fmaf(v, Wn1[j2],     bn1[j2]     + temb[j2]);
    float h1 = fmaf(v, Wn1[j2 + 1], bn1[j2 + 1] + temb[j2 + 1]);
    *(float2*)(h + (size_t)n * 128 + j2) = make_float2(h0, h1);
    h16u[(size_t)n * 64 + (j2 >> 1)] = packbf(h0, h1);
}

// ------------ layers 2/3: pull aggregation (bf16 h gather), unroll 4 ------------
__global__ __launch_bounds__(256) void aggL_kernel(
    const uint* __restrict__ h16u, const uint4* __restrict__ epack,
    const int* __restrict__ rowstart,
    const float* __restrict__ P, const float* __restrict__ Q,
    const float* __restrict__ R, float* __restrict__ agg, int N)
{
    int v = blockIdx.x * 4 + (threadIdx.x >> 6);
    int lane = threadIdx.x & 63;
    if (v >= N) return;
    int c = lane * 2;
    float2 Pv = *(const float2*)(P + c);
    float2 Qv = *(const float2*)(Q + c);
    float2 Rv = *(const float2*)(R + c);
    int beg = rowstart[v], end = rowstart[v + 1];
    float accx = 0.0f, accy = 0.0f;
    int i = beg;
    for (; i + 4 <= end; i += 4) {
        uint4 pk0 = epack[i];
        uint4 pk1 = epack[i + 1];
        uint4 pk2 = epack[i + 2];
        uint4 pk3 = epack[i + 3];
        uint hp0 = h16u[(size_t)pk0.y * 64 + lane];
        uint hp1 = h16u[(size_t)pk1.y * 64 + lane];
        uint hp2 = h16u[(size_t)pk2.y * 64 + lane];
        uint hp3 = h16u[(size_t)pk3.y * 64 + lane];
        float a0 = __uint_as_float(pk0.z), b0 = __uint_as_float(pk0.w);
        float a1 = __uint_as_float(pk1.z), b1 = __uint_as_float(pk1.w);
        float a2 = __uint_as_float(pk2.z), b2 = __uint_as_float(pk2.w);
        float a3 = __uint_as_float(pk3.z), b3 = __uint_as_float(pk3.w);
        accx += fmaxf(bf2f_lo(hp0) + fmaf(a0, Pv.x, fmaf(b0, Qv.x, Rv.x)), 0.0f);
        accy += fmaxf(bf2f_hi(hp0) + fmaf(a0, Pv.y, fmaf(b0, Qv.y, Rv.y)), 0.0f);
        accx += fmaxf(bf2f_lo(hp1) + fmaf(a1, Pv.x, fmaf(b1, Qv.x, Rv.x)), 0.0f);
        accy += fmaxf(bf2f_hi(hp1) + fmaf(a1, Pv.y, fmaf(b1, Qv.y, Rv.y)), 0.0f);
        accx += fmaxf(bf2f_lo(hp2) + fmaf(a2, Pv.x, fmaf(b2, Qv.x, Rv.x)), 0.0f);
        accy += fmaxf(bf2f_hi(hp2) + fmaf(a2, Pv.y, fmaf(b2, Qv.y, Rv.y)), 0.0f);
        accx += fmaxf(bf2f_lo(hp3) + fmaf(a3, Pv.x, fmaf(b3, Qv.x, Rv.x)), 0.0f);
        accy += fmaxf(bf2f_hi(hp3) + fmaf(a3, Pv.y, fmaf(b3, Qv.y, Rv.y)), 0.0f);
    }
    for (; i < end; i++) {
        uint4 pk = epack[i];
        float a = __uint_as_float(pk.z), b = __uint_as_float(pk.w);
        uint hp = h16u[(size_t)pk.y * 64 + lane];
        accx += fmaxf(bf2f_lo(hp) + fmaf(a, Pv.x, fmaf(b, Qv.x, Rv.x)), 0.0f);
        accy += fmaxf(bf2f_hi(hp) + fmaf(a, Pv.y, fmaf(b, Qv.y, Rv.y)), 0.0f);
    }
    *(float2*)(agg + (size_t)v * 128 + c) = make_float2(accx, accy);
}

// ----- layer 2 node update: 64 nodes/block, 8n x 4o per thread, k-blocked b128 ----
__global__ __launch_bounds__(256) void nodeL_kernel(
    float* __restrict__ h, const float* __restrict__ agg,
    const float* __restrict__ W, const float* __restrict__ bn,
    const float* __restrict__ temb, uint* __restrict__ h16u, int N)
{
    __shared__ float vs[64][128];   // 32 KB
    int nb = blockIdx.x * 64;
    int tid = threadIdx.x;
    for (int idx = tid; idx < 64 * 32; idx += 256) {
        int n = idx >> 5, c = (idx & 31) * 4;
        float4 a = make_float4(0.f, 0.f, 0.f, 0.f);
        if (nb + n < N) {
            a = *(const float4*)(h + (size_t)(nb + n) * 128 + c);
            float4 g = *(const float4*)(agg + (size_t)(nb + n) * 128 + c);
            a.x += g.x; a.y += g.y; a.z += g.z; a.w += g.w;
        }
        *(float4*)(&vs[n][c]) = a;
    }
    __syncthreads();
    int o0 = (tid & 31) * 4;      // output cols o0..o0+3
    int n0 = (tid >> 5) * 8;      // nodes n0..n0+7 (local)
    float acc[8][4];
    float4 bb = *(const float4*)(bn + o0);
    float4 tb = *(const float4*)(temb + o0);
    bb.x += tb.x; bb.y += tb.y; bb.z += tb.z; bb.w += tb.w;
#pragma unroll
    for (int i = 0; i < 8; i++) {
        acc[i][0] = bb.x; acc[i][1] = bb.y; acc[i][2] = bb.z; acc[i][3] = bb.w;
    }
    for (int k = 0; k < 128; k += 4) {
        float hv[8][4];
#pragma unroll
        for (int i = 0; i < 8; i++)
            *(float4*)hv[i] = *(const float4*)(&vs[n0 + i][k]);
#pragma unroll
        for (int kk = 0; kk < 4; kk++) {
            float4 wv = *(const float4*)(W + (k + kk) * 128 + o0);
#pragma unroll
            for (int i = 0; i < 8; i++) {
                float hvv = hv[i][kk];
                acc[i][0] = fmaf(hvv, wv.x, acc[i][0]);
                acc[i][1] = fmaf(hvv, wv.y, acc[i][1]);
                acc[i][2] = fmaf(hvv, wv.z, acc[i][2]);
                acc[i][3] = fmaf(hvv, wv.w, acc[i][3]);
            }
        }
    }
#pragma unroll
    for (int i = 0; i < 8; i++) {
        int n = nb + n0 + i;
        if (n < N) {
            *(float4*)(h + (size_t)n * 128 + o0) =
                make_float4(acc[i][0], acc[i][1], acc[i][2], acc[i][3]);
            uint2 pk;
            pk.x = packbf(acc[i][0], acc[i][1]);
            pk.y = packbf(acc[i][2], acc[i][3]);
            *(uint2*)(h16u + (size_t)n * 64 + (o0 >> 1)) = pk;
        }
    }
}

// ------- fused layer-3 node update + decode A/B precompute (h3 stays in LDS) -------
// phase1: 2n x 4o, k-blocked ; phase2: 4n x 8o, k-blocked, A/B split by tid>>7
__global__ __launch_bounds__(256) void node3_decode_kernel(
    const float* __restrict__ h, const float* __restrict__ agg,
    const float* __restrict__ Wn3, const float* __restrict__ bn3,
    const float* __restrict__ temb, const float* __restrict__ Wp,
    const float* __restrict__ bd1, ushort* __restrict__ A16s,
    ushort* __restrict__ B16s, int N)
{
    __shared__ float vs[16][128];
    __shared__ float hs3[16][128];
    int nb = blockIdx.x * 16;
    int tid = threadIdx.x;
    for (int idx = tid; idx < 16 * 32; idx += 256) {
        int n = idx >> 5, c = (idx & 31) * 4;
        float4 a = make_float4(0.f, 0.f, 0.f, 0.f);
        if (nb + n < N) {
            a = *(const float4*)(h + (size_t)(nb + n) * 128 + c);
            float4 g = *(const float4*)(agg + (size_t)(nb + n) * 128 + c);
            a.x += g.x; a.y += g.y; a.z += g.z; a.w += g.w;
        }
        *(float4*)(&vs[n][c]) = a;
    }
    __syncthreads();
    // phase 1: h3 = vs @ Wn3 + bn3 + temb  -> hs3
    {
        int o0 = (tid & 31) * 4;
        int n0 = (tid >> 5) * 2;
        float acc[2][4];
        float4 bb = *(const float4*)(bn3 + o0);
        float4 tb = *(const float4*)(temb + o0);
        bb.x += tb.x; bb.y += tb.y; bb.z += tb.z; bb.w += tb.w;
#pragma unroll
        for (int i = 0; i < 2; i++) {
            acc[i][0] = bb.x; acc[i][1] = bb.y; acc[i][2] = bb.z; acc[i][3] = bb.w;
        }
        for (int k = 0; k < 128; k += 4) {
            float hv0[4], hv1[4];
            *(float4*)hv0 = *(const float4*)(&vs[n0][k]);
            *(float4*)hv1 = *(const float4*)(&vs[n0 + 1][k]);
#pragma unroll
            for (int kk = 0; kk < 4; kk++) {
                float4 wv = *(const float4*)(Wn3 + (k + kk) * 128 + o0);
                acc[0][0] = fmaf(hv0[kk], wv.x, acc[0][0]);
                acc[0][1] = fmaf(hv0[kk], wv.y, acc[0][1]);
                acc[0][2] = fmaf(hv0[kk], wv.z, acc[0][2]);
                acc[0][3] = fmaf(hv0[kk], wv.w, acc[0][3]);
                acc[1][0] = fmaf(hv1[kk], wv.x, acc[1][0]);
                acc[1][1] = fmaf(hv1[kk], wv.y, acc[1][1]);
                acc[1][2] = fmaf(hv1[kk], wv.z, acc[1][2]);
                acc[1][3] = fmaf(hv1[kk], wv.w, acc[1][3]);
            }
        }
        __syncthreads();   // vs no longer needed
#pragma unroll
        for (int i = 0; i < 2; i++)
            *(float4*)(&hs3[n0 + i][o0]) =
                make_float4(acc[i][0], acc[i][1], acc[i][2], acc[i][3]);
    }
    __syncthreads();
    // phase 2: A = hs3 @ Wp[0:128] + bd1 ; B = hs3 @ Wp[128:256]  (4n x 8o per thread)
    {
        int half = tid >> 7;            // 0 = A, 1 = B
        int slot = tid & 127;
        int o0 = (slot & 31) * 8;       // 0..248
        int n0 = (slot >> 5) * 4;       // 0,4,8,12
        const float* W = Wp + (size_t)half * 128 * 260;
        ushort* OUT = half ? B16s : A16s;
        float acc[4][8];
        float bias[8] = {0, 0, 0, 0, 0, 0, 0, 0};
        if (!half) {
            *(float4*)(&bias[0]) = *(const float4*)(bd1 + o0);
            *(float4*)(&bias[4]) = *(const float4*)(bd1 + o0 + 4);
        }
#pragma unroll
        for (int i = 0; i < 4; i++)
#pragma unroll
            for (int j = 0; j < 8; j++) acc[i][j] = bias[j];
        for (int k = 0; k < 128; k += 4) {
            float hv[4][4];
#pragma unroll
            for (int i = 0; i < 4; i++)
                *(float4*)hv[i] = *(const float4*)(&hs3[n0 + i][k]);
#pragma unroll
            for (int kk = 0; kk < 4; kk++) {
                float4 wa = *(const float4*)(W + (k + kk) * 260 + o0);
                float4 wb = *(const float4*)(W + (k + kk) * 260 + o0 + 4);
#pragma unroll
                for (int i = 0; i < 4; i++) {
                    float hvv = hv[i][kk];
                    acc[i][0] = fmaf(hvv, wa.x, acc[i][0]);
                    acc[i][1] = fmaf(hvv, wa.y, acc[i][1]);
                    acc[i][2] = fmaf(hvv, wa.z, acc[i][2]);
                    acc[i][3] = fmaf(hvv, wa.w, acc[i][3]);
                    acc[i][4] = fmaf(hvv, wb.x, acc[i][4]);
                    acc[i][5] = fmaf(hvv, wb.y, acc[i][5]);
                    acc[i][6] = fmaf(hvv, wb.z, acc[i][6]);
                    acc[i][7] = fmaf(hvv, wb.w, acc[i][7]);
                }
            }
        }
#pragma unroll
        for (int i = 0; i < 4; i++) {
            int n = nb + n0 + i;
            if (n < N) {
                uint4 pk;
                pk.x = packbf(acc[i][0], acc[i][1]);
                pk.y = packbf(acc[i][2], acc[i][3]);
                pk.z = packbf(acc[i][4], acc[i][5]);
                pk.w = packbf(acc[i][6], acc[i][7]);
                *(uint4*)((uint*)OUT + (size_t)n * AB_U + (o0 >> 1)) = pk;
            }
        }
    }
    // tail: o = 256 column for A and B (16 threads, one per node)
    if (tid < 16) {
        int n = tid;
        float sA = bd1[256], sB = 0.f;
        for (int k = 0; k < 128; k++) {
            float hv = hs3[n][k];
            sA = fmaf(hv, Wp[k * 260 + 256], sA);
            sB = fmaf(hv, Wp[(128 + k) * 260 + 256], sB);
        }
        if (nb + n < N) {
            A16s[(size_t)(nb + n) * 264 + 256] = f2bf(sA);
            B16s[(size_t)(nb + n) * 264 + 256] = f2bf(sB);
        }
    }
}

// ---- decode edges, dst-grouped: wave per node, bf16 A gather, B in regs, unroll 2 ----
__global__ __launch_bounds__(256) void decodeE_kernel(
    const uint* __restrict__ A16u, const uint* __restrict__ B16u,
    const uint4* __restrict__ epack, const int* __restrict__ rowstart,
    const float* __restrict__ Wd1, const float* __restrict__ Wd2,
    const float* __restrict__ bd2, float* __restrict__ out, int N)
{
    int v = blockIdx.x * 4 + (threadIdx.x >> 6);
    int lane = threadIdx.x & 63;
    if (v >= N) return;
    const float* w256 = Wd1 + 256 * 257;
    float4 w2v = *(const float4*)(w256 + lane * 4);
    float4 wdv = *(const float4*)(Wd2 + lane * 4);
    const uint* Br = B16u + (size_t)v * AB_U;
    uint2 bp = *(const uint2*)(Br + lane * 2);
    float Bv0 = bf2f_lo(bp.x), Bv1 = bf2f_hi(bp.x);
    float Bv2 = bf2f_lo(bp.y), Bv3 = bf2f_hi(bp.y);
    float w2_l = w256[256], wd_l = Wd2[256], bd = bd2[0];
    float B_l = bf2f_lo(Br[128]);
    int beg = rowstart[v], end = rowstart[v + 1];
    int i = beg;
    for (; i + 2 <= end; i += 2) {
        uint4 pk0 = epack[i];
        uint4 pk1 = epack[i + 1];
        float q0 = __uint_as_float(pk0.w);
        float q1 = __uint_as_float(pk1.w);
        const uint* Ar0 = A16u + (size_t)pk0.y * AB_U;
        const uint* Ar1 = A16u + (size_t)pk1.y * AB_U;
        uint2 ap0 = *(const uint2*)(Ar0 + lane * 2);
        uint2 ap1 = *(const uint2*)(Ar1 + lane * 2);
        float t0 = 0.f, t1 = 0.f;
        if (lane == 0) {
            t0 = bf2f_lo(Ar0[128]);
            t1 = bf2f_lo(Ar1[128]);
        }
        float y00 = bf2f_lo(ap0.x) + fmaf(q0, w2v.x, Bv0);
        float y01 = bf2f_hi(ap0.x) + fmaf(q0, w2v.y, Bv1);
        float y02 = bf2f_lo(ap0.y) + fmaf(q0, w2v.z, Bv2);
        float y03 = bf2f_hi(ap0.y) + fmaf(q0, w2v.w, Bv3);
        float acc0 = fmaxf(y00, 0.f) * wdv.x + fmaxf(y01, 0.f) * wdv.y
                   + fmaxf(y02, 0.f) * wdv.z + fmaxf(y03, 0.f) * wdv.w;
        float y10 = bf2f_lo(ap1.x) + fmaf(q1, w2v.x, Bv0);
        float y11 = bf2f_hi(ap1.x) + fmaf(q1, w2v.y, Bv1);
        float y12 = bf2f_lo(ap1.y) + fmaf(q1, w2v.z, Bv2);
        float y13 = bf2f_hi(ap1.y) + fmaf(q1, w2v.w, Bv3);
        float acc1 = fmaxf(y10, 0.f) * wdv.x + fmaxf(y11, 0.f) * wdv.y
                   + fmaxf(y12, 0.f) * wdv.z + fmaxf(y13, 0.f) * wdv.w;
        if (lane == 0) {
            acc0 = fmaf(fmaxf(t0 + fmaf(q0, w2_l, B_l), 0.f), wd_l, acc0);
            acc1 = fmaf(fmaxf(t1 + fmaf(q1, w2_l, B_l), 0.f), wd_l, acc1);
        }
#pragma unroll
        for (int off = 32; off > 0; off >>= 1) {
            acc0 += __shfl_xor(acc0, off, 64);
            acc1 += __shfl_xor(acc1, off, 64);
        }
        if (lane == 0) {
            out[(int)pk0.x] = acc0 + bd;
            out[(int)pk1.x] = acc1 + bd;
        }
    }
    if (i < end) {
        uint4 pk = epack[i];
        float q = __uint_as_float(pk.w);
        const uint* Ar = A16u + (size_t)pk.y * AB_U;
        uint2 ap = *(const uint2*)(Ar + lane * 2);
        float y0 = bf2f_lo(ap.x) + fmaf(q, w2v.x, Bv0);
        float y1 = bf2f_hi(ap.x) + fmaf(q, w2v.y, Bv1);
        float y2 = bf2f_lo(ap.y) + fmaf(q, w2v.z, Bv2);
        float y3 = bf2f_hi(ap.y) + fmaf(q, w2v.w, Bv3);
        float acc = fmaxf(y0, 0.f) * wdv.x + fmaxf(y1, 0.f) * wdv.y
                  + fmaxf(y2, 0.f) * wdv.z + fmaxf(y3, 0.f) * wdv.w;
        if (lane == 0) {
            float yl = bf2f_lo(Ar[128]) + fmaf(q, w2_l, B_l);
            acc = fmaf(fmaxf(yl, 0.f), wd_l, acc);
        }
#pragma unroll
        for (int off = 32; off > 0; off >>= 1) acc += __shfl_xor(acc, off, 64);
        if (lane == 0) out[(int)pk.x] = acc + bd;
    }
}

extern "C" void kernel_launch(void* const* d_in, const int* in_sizes, int n_in,
                              void* d_out, int out_size, void* d_ws, size_t ws_size,
                              hipStream_t stream) {
    (void)n_in; (void)out_size; (void)ws_size;
    const float* x   = (const float*)d_in[0];
    const float* ea  = (const float*)d_in[1];
    const float* qy  = (const float*)d_in[2];
    const int*   adj = (const int*)d_in[3];
    const float* t   = (const float*)d_in[4];
    // d_in[5]=num_steps (unused), d_in[6]=batch (unused)
    const float* We  = (const float*)d_in[7];
    const float* be  = (const float*)d_in[8];
    const float* Wo  = (const float*)d_in[9];
    const float* bo  = (const float*)d_in[10];
    const float* Wl1 = (const float*)d_in[11];
    const float* bl1 = (const float*)d_in[12];
    const float* Wn1 = (const float*)d_in[13];
    const float* bn1 = (const float*)d_in[14];
    const float* Wl2 = (const float*)d_in[15];
    const float* bl2 = (const float*)d_in[16];
    const float* Wn2 = (const float*)d_in[17];
    const float* bn2 = (const float*)d_in[18];
    const float* Wl3 = (const float*)d_in[19];
    const float* bl3 = (const float*)d_in[20];
    const float* Wn3 = (const float*)d_in[21];
    const float* bn3 = (const float*)d_in[22];
    const float* Wt1 = (const float*)d_in[23];
    const float* bt1 = (const float*)d_in[24];
    const float* Wt2 = (const float*)d_in[25];
    const float* bt2 = (const float*)d_in[26];
    const float* Wd1 = (const float*)d_in[27];
    const float* bd1 = (const float*)d_in[28];
    const float* Wd2 = (const float*)d_in[29];
    const float* bd2 = (const float*)d_in[30];
    float* out = (float*)d_out;

    int N = in_sizes[0];
    int E = in_sizes[3] / 2;
    const int* src = adj;
    const int* dst = adj + E;

    float* w    = (float*)d_ws;
    float* temb = w;            // wsmall block (1024 floats)
    float* P2   = w + 128;
    float* Q2   = w + 256;
    float* R2   = w + 384;
    float* P3   = w + 512;
    float* Q3   = w + 640;
    float* R3   = w + 768;
    float* scal = w + 896;
    float* h    = w + 1024;                         // N*128 f32
    float* agg  = h + (size_t)N * 128;              // N*128 f32 (first N = agg1)
    uint*  h16u = (uint*)(agg + (size_t)N * 128);   // N*64 uints (bf16 pairs)
    uint*  A16u = h16u + (size_t)N * 64;            // N*AB_U uints
    uint*  B16u = A16u + (size_t)N * AB_U;          // N*AB_U uints
    int* rowstart = (int*)(B16u + (size_t)N * AB_U);  // N+1
    int* cursor   = rowstart + (N + 1);               // N (hist cnt / scatter cursor)
    int* partials = cursor + N;                       // scan partials
    int nblk = (N + 1023) / 1024;
    char* pcur = (char*)(partials + nblk + 1);
    pcur = (char*)(((uintptr_t)pcur + 15) & ~(uintptr_t)15);
    uint4* epack = (uint4*)pcur;                      // E * 16B
    float* Wp = (float*)(epack + E);                  // 256*260 f32 (aligned Wd1 copy)

    // ---- CSR build (by dst) ----
    hipMemsetAsync(cursor, 0, (size_t)N * sizeof(int), stream);
    hist_kernel<<<(E + 255) / 256, 256, 0, stream>>>(dst, cursor, E);
    scan1_kernel<<<nblk, 256, 0, stream>>>(cursor, rowstart, partials, N);
    scan2_kernel<<<1, 64, 0, stream>>>(partials, rowstart, nblk, N);
    scan3_kernel<<<(N + 255) / 256, 256, 0, stream>>>(rowstart, partials, N);
    hipMemsetAsync(cursor, 0, (size_t)N * sizeof(int), stream);
    scatter_kernel<<<(E + 255) / 256, 256, 0, stream>>>(src, dst, ea, qy, rowstart, cursor, epack, E);

    wp_kernel<<<256, 256, 0, stream>>>(Wd1, Wp);
    precompute_kernel<<<1, 256, 0, stream>>>(t, We, be, Wo, bo, Wl1, bl1,
                                             Wl2, bl2, Wl3, bl3,
                                             Wt1, bt1, Wt2, bt2, w);
    // layer 1
    edge1_kernel<<<(N + 255) / 256, 256, 0, stream>>>(x, epack, rowstart, scal, agg, N);
    node1_kernel<<<(N * 64 + 255) / 256, 256, 0, stream>>>(x, agg, Wn1, bn1, temb, h, h16u, N);
    // layer 2
    aggL_kernel<<<(N + 3) / 4, 256, 0, stream>>>(h16u, epack, rowstart, P2, Q2, R2, agg, N);
    nodeL_kernel<<<(N + 63) / 64, 256, 0, stream>>>(h, agg, Wn2, bn2, temb, h16u, N);
    // layer 3 (node update fused with decode A/B precompute)
    aggL_kernel<<<(N + 3) / 4, 256, 0, stream>>>(h16u, epack, rowstart, P3, Q3, R3, agg, N);
    node3_decode_kernel<<<(N + 15) / 16, 256, 0, stream>>>(h, agg, Wn3, bn3, temb, Wp, bd1,
                                                           (ushort*)A16u, (ushort*)B16u, N);
    // decode edges
    decodeE_kernel<<<(N + 3) / 4, 256, 0, stream>>>(A16u, B16u, epack, rowstart, Wd1, Wd2, bd2, out, N);
}

// Round 10
// 573.506 us; speedup vs baseline: 1.1006x; 1.1006x over previous
//
#include <hip/hip_runtime.h>

typedef unsigned int uint;
typedef unsigned short ushort;

#define AB_U 132  // A/B row stride in uints (264 bf16 elems, 257 used)

typedef __attribute__((ext_vector_type(8))) short short8;
typedef __attribute__((ext_vector_type(4))) float f32x4;
union U4S8 { uint4 u; short8 s; };

__device__ __forceinline__ ushort f2bf(float f) {
    uint u = __float_as_uint(f);
    u += 0x7FFFu + ((u >> 16) & 1u);   // round-to-nearest-even
    return (ushort)(u >> 16);
}
__device__ __forceinline__ float bf2f_lo(uint p) { return __uint_as_float(p << 16); }
__device__ __forceinline__ float bf2f_hi(uint p) { return __uint_as_float(p & 0xFFFF0000u); }
__device__ __forceinline__ uint packbf(float lo, float hi) {
    return (uint)f2bf(lo) | ((uint)f2bf(hi) << 16);
}

// ---------------- precompute: temb MLP + rank-2 edge-lin factors ----------------
// wsmall layout (floats): temb[0:128] P2[128:256] Q2[256:384] R2[384:512]
//                         P3[512:640] Q3[640:768] R3[768:896] scal[896:899]
__global__ __launch_bounds__(256) void precompute_kernel(
    const float* __restrict__ t,
    const float* __restrict__ We, const float* __restrict__ be,
    const float* __restrict__ Wo, const float* __restrict__ bo,
    const float* __restrict__ Wl1, const float* __restrict__ bl1,
    const float* __restrict__ Wl2, const float* __restrict__ bl2,
    const float* __restrict__ Wl3, const float* __restrict__ bl3,
    const float* __restrict__ Wt1, const float* __restrict__ bt1,
    const float* __restrict__ Wt2, const float* __restrict__ bt2,
    float* __restrict__ wsmall)
{
    __shared__ float t0[128];
    __shared__ float y1[256];
    int tid = threadIdx.x;
    float tt = t[0] * 4.0f;
    if (tid < 64) {
        float f = expf(-logf(10000.0f) * (float)tid / 63.0f);
        float v = tt * f;
        t0[tid]      = sinf(v);
        t0[tid + 64] = cosf(v);
    }
    __syncthreads();
    {
        float acc = bt1[tid];
        for (int k = 0; k < 128; k++) acc = fmaf(t0[k], Wt1[k * 256 + tid], acc);
        y1[tid] = fmaxf(acc, 0.0f);
    }
    __syncthreads();
    if (tid < 128) {
        float a = bt2[tid];
        for (int k = 0; k < 256; k++) a = fmaf(y1[k], Wt2[k * 128 + tid], a);
        wsmall[tid] = a;  // temb
    }
    {
        int j = tid & 127;
        const float* Wl  = (tid < 128) ? Wl2 : Wl3;
        const float* blp = (tid < 128) ? bl2 : bl3;
        float p = 0.f, q = 0.f, r = blp[j];
        for (int k = 0; k < 64; k++) {
            float w1 = Wl[k * 128 + j], w2 = Wl[(64 + k) * 128 + j];
            p = fmaf(We[k], w1, p);
            q = fmaf(Wo[k], w2, q);
            r = fmaf(be[k], w1, r);
            r = fmaf(bo[k], w2, r);
        }
        int base = (tid < 128) ? 128 : 512;
        wsmall[base + j]       = p;
        wsmall[base + 128 + j] = q;
        wsmall[base + 256 + j] = r;
    }
    if (tid == 0) {
        float p1 = 0.f, q1 = 0.f, r1 = bl1[0];
        for (int k = 0; k < 64; k++) {
            p1 = fmaf(We[k], Wl1[k], p1);
            q1 = fmaf(Wo[k], Wl1[64 + k], q1);
            r1 = fmaf(be[k], Wl1[k], r1);
            r1 = fmaf(bo[k], Wl1[64 + k], r1);
        }
        wsmall[896] = p1; wsmall[897] = q1; wsmall[898] = r1;
    }
}

// stage Wd1 columns as bf16, transposed: Wt16u[c][k-pairs], c in [0,512)
// c<256: A-weights rows k=0..127 ; c>=256: B-weights rows k=128..255
__global__ __launch_bounds__(64) void wt16_kernel(
    const float* __restrict__ Wd1, uint* __restrict__ Wt16u)
{
    int c = blockIdx.x;      // 0..511
    int u = threadIdx.x;     // 0..63 (k-pair)
    int k = u * 2;
    float lo, hi;
    if (c < 256) {
        lo = Wd1[k * 257 + c];
        hi = Wd1[(k + 1) * 257 + c];
    } else {
        int cc = c - 256;
        lo = Wd1[(128 + k) * 257 + cc];
        hi = Wd1[(128 + k + 1) * 257 + cc];
    }
    Wt16u[c * 64 + u] = packbf(lo, hi);
}

// ---------------- CSR build: histogram -> hierarchical scan -> scatter ----------------
__global__ __launch_bounds__(256) void hist_kernel(
    const int* __restrict__ dst, int* __restrict__ cnt, int E)
{
    int e = blockIdx.x * blockDim.x + threadIdx.x;
    if (e < E) atomicAdd(&cnt[dst[e]], 1);
}

// per-block (1024 elems) exclusive scan; block total -> partials[b]
__global__ __launch_bounds__(256) void scan1_kernel(
    const int* __restrict__ cnt, int* __restrict__ rowstart,
    int* __restrict__ partials, int N)
{
    __shared__ int wsum[4];
    int b = blockIdx.x;
    int tid = threadIdx.x, lane = tid & 63, w = tid >> 6;
    int i0 = b * 1024 + tid * 4;
    int v0 = (i0     < N) ? cnt[i0]     : 0;
    int v1 = (i0 + 1 < N) ? cnt[i0 + 1] : 0;
    int v2 = (i0 + 2 < N) ? cnt[i0 + 2] : 0;
    int v3 = (i0 + 3 < N) ? cnt[i0 + 3] : 0;
    int tsum = v0 + v1 + v2 + v3;
    int s = tsum;
#pragma unroll
    for (int off = 1; off < 64; off <<= 1) {
        int u = __shfl_up(s, off, 64);
        if (lane >= off) s += u;
    }
    if (lane == 63) wsum[w] = s;
    __syncthreads();
    int woff = 0;
    for (int k = 0; k < w; k++) woff += wsum[k];
    int ex = woff + s - tsum;
    if (i0     < N) rowstart[i0]     = ex;
    if (i0 + 1 < N) rowstart[i0 + 1] = ex + v0;
    if (i0 + 2 < N) rowstart[i0 + 2] = ex + v0 + v1;
    if (i0 + 3 < N) rowstart[i0 + 3] = ex + v0 + v1 + v2;
    if (tid == 255) partials[b] = woff + s;
}

// single wave: exclusive scan of partials; also writes rowstart[N] = total
__global__ __launch_bounds__(64) void scan2_kernel(
    int* __restrict__ partials, int* __restrict__ rowstart, int nblk, int N)
{
    int lane = threadIdx.x;
    int carry = 0;
    for (int base = 0; base < nblk; base += 64) {
        int i = base + lane;
        int v = (i < nblk) ? partials[i] : 0;
        int s = v;
#pragma unroll
        for (int off = 1; off < 64; off <<= 1) {
            int u = __shfl_up(s, off, 64);
            if (lane >= off) s += u;
        }
        if (i < nblk) partials[i] = carry + s - v;
        carry += __shfl(s, 63, 64);
    }
    if (lane == 0) rowstart[N] = carry;
}

__global__ __launch_bounds__(256) void scan3_kernel(
    int* __restrict__ rowstart, const int* __restrict__ partials, int N)
{
    int i = blockIdx.x * blockDim.x + threadIdx.x;
    if (i < N) rowstart[i] += partials[i >> 10];
}

// scatter: build dst-grouped edge payload {e, src, ea, qy}
__global__ __launch_bounds__(256) void scatter_kernel(
    const int* __restrict__ src, const int* __restrict__ dst,
    const float* __restrict__ ea, const float* __restrict__ qy,
    const int* __restrict__ rowstart, int* __restrict__ cursor,
    uint4* __restrict__ epack, int E)
{
    int e = blockIdx.x * blockDim.x + threadIdx.x;
    if (e >= E) return;
    int d = dst[e];
    int pos = atomicAdd(&cursor[d], 1);
    uint4 pk;
    pk.x = (uint)e;
    pk.y = (uint)src[e];
    pk.z = __float_as_uint(ea[e]);
    pk.w = __float_as_uint(qy[e]);
    epack[rowstart[d] + pos] = pk;
}

// ---------------- layer 1 (scalar channel), pull over CSR, unroll 2 ----------------
__global__ __launch_bounds__(256) void edge1_kernel(
    const float* __restrict__ x, const uint4* __restrict__ epack,
    const int* __restrict__ rowstart, const float* __restrict__ scal,
    float* __restrict__ agg1, int N)
{
    int v = blockIdx.x * blockDim.x + threadIdx.x;
    if (v >= N) return;
    float s0 = scal[0], s1 = scal[1], s2 = scal[2];
    int beg = rowstart[v], end = rowstart[v + 1];
    float m = 0.0f;
    int i = beg;
    for (; i + 2 <= end; i += 2) {
        uint4 pk0 = epack[i];
        uint4 pk1 = epack[i + 1];
        float x0 = x[(int)pk0.y];
        float x1 = x[(int)pk1.y];
        m += fmaxf(x0 + fmaf(__uint_as_float(pk0.z), s0, fmaf(__uint_as_float(pk0.w), s1, s2)), 0.0f);
        m += fmaxf(x1 + fmaf(__uint_as_float(pk1.z), s0, fmaf(__uint_as_float(pk1.w), s1, s2)), 0.0f);
    }
    if (i < end) {
        uint4 pk = epack[i];
        m += fmaxf(x[(int)pk.y] + fmaf(__uint_as_float(pk.z), s0, fmaf(__uint_as_float(pk.w), s1, s2)), 0.0f);
    }
    agg1[v] = m;
}

// h1 = (x+agg1)*Wn1 + bn1 + temb ; also bf16 shadow
__global__ __launch_bounds__(256) void node1_kernel(
    const float* __restrict__ x, const float* __restrict__ agg1,
    const float* __restrict__ Wn1, const float* __restrict__ bn1,
    const float* __restrict__ temb, float* __restrict__ h,
    uint* __restrict__ h16u, int N)
{
    int i = blockIdx.x * blockDim.x + threadIdx.x;  // N*64 threads
    int n = i >> 6, j2 = (i & 63) * 2;
    if (n >= N) return;
    float v = x[n] + agg1[n];
    float h0 = fmaf(v, Wn1[j2],     bn1[j2]     + temb[j2]);
    float h1 = fmaf(v, Wn1[j2 + 1], bn1[j2 + 1] + temb[j2 + 1]);
    *(float2*)(h + (size_t)n * 128 + j2) = make_float2(h0, h1);
    h16u[(size_t)n * 64 + (j2 >> 1)] = packbf(h0, h1);
}

// ------------ layers 2/3: pull aggregation (bf16 h gather), unroll 4 ------------
__global__ __launch_bounds__(256) void aggL_kernel(
    const uint* __restrict__ h16u, const uint4* __restrict__ epack,
    const int* __restrict__ rowstart,
    const float* __restrict__ P, const float* __restrict__ Q,
    const float* __restrict__ R, float* __restrict__ agg, int N)
{
    int v = blockIdx.x * 4 + (threadIdx.x >> 6);
    int lane = threadIdx.x & 63;
    if (v >= N) return;
    int c = lane * 2;
    float2 Pv = *(const float2*)(P + c);
    float2 Qv = *(const float2*)(Q + c);
    float2 Rv = *(const float2*)(R + c);
    int beg = rowstart[v], end = rowstart[v + 1];
    float accx = 0.0f, accy = 0.0f;
    int i = beg;
    for (; i + 4 <= end; i += 4) {
        uint4 pk0 = epack[i];
        uint4 pk1 = epack[i + 1];
        uint4 pk2 = epack[i + 2];
        uint4 pk3 = epack[i + 3];
        uint hp0 = h16u[(size_t)pk0.y * 64 + lane];
        uint hp1 = h16u[(size_t)pk1.y * 64 + lane];
        uint hp2 = h16u[(size_t)pk2.y * 64 + lane];
        uint hp3 = h16u[(size_t)pk3.y * 64 + lane];
        float a0 = __uint_as_float(pk0.z), b0 = __uint_as_float(pk0.w);
        float a1 = __uint_as_float(pk1.z), b1 = __uint_as_float(pk1.w);
        float a2 = __uint_as_float(pk2.z), b2 = __uint_as_float(pk2.w);
        float a3 = __uint_as_float(pk3.z), b3 = __uint_as_float(pk3.w);
        accx += fmaxf(bf2f_lo(hp0) + fmaf(a0, Pv.x, fmaf(b0, Qv.x, Rv.x)), 0.0f);
        accy += fmaxf(bf2f_hi(hp0) + fmaf(a0, Pv.y, fmaf(b0, Qv.y, Rv.y)), 0.0f);
        accx += fmaxf(bf2f_lo(hp1) + fmaf(a1, Pv.x, fmaf(b1, Qv.x, Rv.x)), 0.0f);
        accy += fmaxf(bf2f_hi(hp1) + fmaf(a1, Pv.y, fmaf(b1, Qv.y, Rv.y)), 0.0f);
        accx += fmaxf(bf2f_lo(hp2) + fmaf(a2, Pv.x, fmaf(b2, Qv.x, Rv.x)), 0.0f);
        accy += fmaxf(bf2f_hi(hp2) + fmaf(a2, Pv.y, fmaf(b2, Qv.y, Rv.y)), 0.0f);
        accx += fmaxf(bf2f_lo(hp3) + fmaf(a3, Pv.x, fmaf(b3, Qv.x, Rv.x)), 0.0f);
        accy += fmaxf(bf2f_hi(hp3) + fmaf(a3, Pv.y, fmaf(b3, Qv.y, Rv.y)), 0.0f);
    }
    for (; i < end; i++) {
        uint4 pk = epack[i];
        float a = __uint_as_float(pk.z), b = __uint_as_float(pk.w);
        uint hp = h16u[(size_t)pk.y * 64 + lane];
        accx += fmaxf(bf2f_lo(hp) + fmaf(a, Pv.x, fmaf(b, Qv.x, Rv.x)), 0.0f);
        accy += fmaxf(bf2f_hi(hp) + fmaf(a, Pv.y, fmaf(b, Qv.y, Rv.y)), 0.0f);
    }
    *(float2*)(agg + (size_t)v * 128 + c) = make_float2(accx, accy);
}

// ----- layer 2 node update: 64 nodes/block, 8n x 4o per thread, k-blocked b128 ----
__global__ __launch_bounds__(256) void nodeL_kernel(
    float* __restrict__ h, const float* __restrict__ agg,
    const float* __restrict__ W, const float* __restrict__ bn,
    const float* __restrict__ temb, uint* __restrict__ h16u, int N)
{
    __shared__ float vs[64][128];   // 32 KB
    int nb = blockIdx.x * 64;
    int tid = threadIdx.x;
    for (int idx = tid; idx < 64 * 32; idx += 256) {
        int n = idx >> 5, c = (idx & 31) * 4;
        float4 a = make_float4(0.f, 0.f, 0.f, 0.f);
        if (nb + n < N) {
            a = *(const float4*)(h + (size_t)(nb + n) * 128 + c);
            float4 g = *(const float4*)(agg + (size_t)(nb + n) * 128 + c);
            a.x += g.x; a.y += g.y; a.z += g.z; a.w += g.w;
        }
        *(float4*)(&vs[n][c]) = a;
    }
    __syncthreads();
    int o0 = (tid & 31) * 4;      // output cols o0..o0+3
    int n0 = (tid >> 5) * 8;      // nodes n0..n0+7 (local)
    float acc[8][4];
    float4 bb = *(const float4*)(bn + o0);
    float4 tb = *(const float4*)(temb + o0);
    bb.x += tb.x; bb.y += tb.y; bb.z += tb.z; bb.w += tb.w;
#pragma unroll
    for (int i = 0; i < 8; i++) {
        acc[i][0] = bb.x; acc[i][1] = bb.y; acc[i][2] = bb.z; acc[i][3] = bb.w;
    }
    for (int k = 0; k < 128; k += 4) {
        float hv[8][4];
#pragma unroll
        for (int i = 0; i < 8; i++)
            *(float4*)hv[i] = *(const float4*)(&vs[n0 + i][k]);
#pragma unroll
        for (int kk = 0; kk < 4; kk++) {
            float4 wv = *(const float4*)(W + (k + kk) * 128 + o0);
#pragma unroll
            for (int i = 0; i < 8; i++) {
                float hvv = hv[i][kk];
                acc[i][0] = fmaf(hvv, wv.x, acc[i][0]);
                acc[i][1] = fmaf(hvv, wv.y, acc[i][1]);
                acc[i][2] = fmaf(hvv, wv.z, acc[i][2]);
                acc[i][3] = fmaf(hvv, wv.w, acc[i][3]);
            }
        }
    }
#pragma unroll
    for (int i = 0; i < 8; i++) {
        int n = nb + n0 + i;
        if (n < N) {
            *(float4*)(h + (size_t)n * 128 + o0) =
                make_float4(acc[i][0], acc[i][1], acc[i][2], acc[i][3]);
            uint2 pk;
            pk.x = packbf(acc[i][0], acc[i][1]);
            pk.y = packbf(acc[i][2], acc[i][3]);
            *(uint2*)(h16u + (size_t)n * 64 + (o0 >> 1)) = pk;
        }
    }
}

// ------- fused layer-3 node update + decode A/B precompute -------
// phase1: scalar f32 2n x 4o -> bf16 h3 in LDS ; phase2: MFMA 16x16x32 bf16
__global__ __launch_bounds__(256) void node3_decode_kernel(
    const float* __restrict__ h, const float* __restrict__ agg,
    const float* __restrict__ Wn3, const float* __restrict__ bn3,
    const float* __restrict__ temb, const uint* __restrict__ Wt16u,
    const float* __restrict__ Wd1, const float* __restrict__ bd1,
    ushort* __restrict__ A16s, ushort* __restrict__ B16s, int N)
{
    __shared__ float vs[16][128];    // 8 KB
    __shared__ uint hs16[16][68];    // h3 as bf16 pairs, padded stride
    int nb = blockIdx.x * 16;
    int tid = threadIdx.x;
    for (int idx = tid; idx < 16 * 32; idx += 256) {
        int n = idx >> 5, c = (idx & 31) * 4;
        float4 a = make_float4(0.f, 0.f, 0.f, 0.f);
        if (nb + n < N) {
            a = *(const float4*)(h + (size_t)(nb + n) * 128 + c);
            float4 g = *(const float4*)(agg + (size_t)(nb + n) * 128 + c);
            a.x += g.x; a.y += g.y; a.z += g.z; a.w += g.w;
        }
        *(float4*)(&vs[n][c]) = a;
    }
    __syncthreads();
    // phase 1: h3 = vs @ Wn3 + bn3 + temb  -> hs16 (bf16)
    {
        int o0 = (tid & 31) * 4;
        int n0 = (tid >> 5) * 2;
        float acc[2][4];
        float4 bb = *(const float4*)(bn3 + o0);
        float4 tb = *(const float4*)(temb + o0);
        bb.x += tb.x; bb.y += tb.y; bb.z += tb.z; bb.w += tb.w;
#pragma unroll
        for (int i = 0; i < 2; i++) {
            acc[i][0] = bb.x; acc[i][1] = bb.y; acc[i][2] = bb.z; acc[i][3] = bb.w;
        }
        for (int k = 0; k < 128; k += 4) {
            float hv0[4], hv1[4];
            *(float4*)hv0 = *(const float4*)(&vs[n0][k]);
            *(float4*)hv1 = *(const float4*)(&vs[n0 + 1][k]);
#pragma unroll
            for (int kk = 0; kk < 4; kk++) {
                float4 wv = *(const float4*)(Wn3 + (k + kk) * 128 + o0);
                acc[0][0] = fmaf(hv0[kk], wv.x, acc[0][0]);
                acc[0][1] = fmaf(hv0[kk], wv.y, acc[0][1]);
                acc[0][2] = fmaf(hv0[kk], wv.z, acc[0][2]);
                acc[0][3] = fmaf(hv0[kk], wv.w, acc[0][3]);
                acc[1][0] = fmaf(hv1[kk], wv.x, acc[1][0]);
                acc[1][1] = fmaf(hv1[kk], wv.y, acc[1][1]);
                acc[1][2] = fmaf(hv1[kk], wv.z, acc[1][2]);
                acc[1][3] = fmaf(hv1[kk], wv.w, acc[1][3]);
            }
        }
#pragma unroll
        for (int i = 0; i < 2; i++) {
            uint2 pk;
            pk.x = packbf(acc[i][0], acc[i][1]);
            pk.y = packbf(acc[i][2], acc[i][3]);
            *(uint2*)(&hs16[n0 + i][o0 >> 1]) = pk;
        }
    }
    __syncthreads();
    // phase 2 (MFMA): [A|B](16 x 512) = h3(16x128, bf16) @ Wt16(128x512, bf16)
    // tiles 0..15 -> A cols 0..255 (+bd1), tiles 16..31 -> B cols 0..255
    {
        int wv = tid >> 6;          // wave 0..3
        int lane = tid & 63;
        int cl = lane & 15;         // col-in-tile / row index
        int g = lane >> 4;          // k-group
        // A fragments: k-chunk kc -> elems k = kc*32 + g*8 + j (lo/hi pair order)
        short8 afr[4];
#pragma unroll
        for (int kc = 0; kc < 4; kc++) {
            U4S8 t;
            t.u = *(const uint4*)(&hs16[cl][kc * 16 + g * 4]);
            afr[kc] = t.s;
        }
#pragma unroll
        for (int tt = 0; tt < 8; tt++) {
            int tile = wv * 8 + tt;
            int c = tile * 16 + cl;            // combined col 0..511
            float bias = (tile < 16) ? bd1[c] : 0.0f;
            f32x4 acc = {bias, bias, bias, bias};
#pragma unroll
            for (int kc = 0; kc < 4; kc++) {
                U4S8 t;
                t.u = *(const uint4*)(Wt16u + (size_t)c * 64 + kc * 16 + g * 4);
                acc = __builtin_amdgcn_mfma_f32_16x16x32_bf16(afr[kc], t.s, acc, 0, 0, 0);
            }
            ushort* OUT = (tile < 16) ? A16s : B16s;
            int oc = (tile < 16) ? c : (c - 256);
#pragma unroll
            for (int r = 0; r < 4; r++) {
                int n = nb + g * 4 + r;        // D row = (lane>>4)*4 + reg
                if (n < N) OUT[(size_t)n * 264 + oc] = f2bf(acc[r]);
            }
        }
    }
    // tail: o = 256 column for A and B (16 threads, one per node), bf16 h3
    if (tid < 16) {
        int n = tid;
        float sA = bd1[256], sB = 0.f;
        for (int u = 0; u < 64; u++) {
            uint pk = hs16[n][u];
            float h0 = bf2f_lo(pk), h1 = bf2f_hi(pk);
            int k = u * 2;
            sA = fmaf(h0, Wd1[k * 257 + 256], sA);
            sA = fmaf(h1, Wd1[(k + 1) * 257 + 256], sA);
            sB = fmaf(h0, Wd1[(128 + k) * 257 + 256], sB);
            sB = fmaf(h1, Wd1[(128 + k + 1) * 257 + 256], sB);
        }
        if (nb + n < N) {
            A16s[(size_t)(nb + n) * 264 + 256] = f2bf(sA);
            B16s[(size_t)(nb + n) * 264 + 256] = f2bf(sB);
        }
    }
}

// ---- decode edges, dst-grouped: wave per node, bf16 A gather, B in regs, unroll 2 ----
__global__ __launch_bounds__(256) void decodeE_kernel(
    const uint* __restrict__ A16u, const uint* __restrict__ B16u,
    const uint4* __restrict__ epack, const int* __restrict__ rowstart,
    const float* __restrict__ Wd1, const float* __restrict__ Wd2,
    const float* __restrict__ bd2, float* __restrict__ out, int N)
{
    int v = blockIdx.x * 4 + (threadIdx.x >> 6);
    int lane = threadIdx.x & 63;
    if (v >= N) return;
    const float* w256 = Wd1 + 256 * 257;
    float4 w2v = *(const float4*)(w256 + lane * 4);
    float4 wdv = *(const float4*)(Wd2 + lane * 4);
    const uint* Br = B16u + (size_t)v * AB_U;
    uint2 bp = *(const uint2*)(Br + lane * 2);
    float Bv0 = bf2f_lo(bp.x), Bv1 = bf2f_hi(bp.x);
    float Bv2 = bf2f_lo(bp.y), Bv3 = bf2f_hi(bp.y);
    float w2_l = w256[256], wd_l = Wd2[256], bd = bd2[0];
    float B_l = bf2f_lo(Br[128]);
    int beg = rowstart[v], end = rowstart[v + 1];
    int i = beg;
    for (; i + 2 <= end; i += 2) {
        uint4 pk0 = epack[i];
        uint4 pk1 = epack[i + 1];
        float q0 = __uint_as_float(pk0.w);
        float q1 = __uint_as_float(pk1.w);
        const uint* Ar0 = A16u + (size_t)pk0.y * AB_U;
        const uint* Ar1 = A16u + (size_t)pk1.y * AB_U;
        uint2 ap0 = *(const uint2*)(Ar0 + lane * 2);
        uint2 ap1 = *(const uint2*)(Ar1 + lane * 2);
        float t0 = 0.f, t1 = 0.f;
        if (lane == 0) {
            t0 = bf2f_lo(Ar0[128]);
            t1 = bf2f_lo(Ar1[128]);
        }
        float y00 = bf2f_lo(ap0.x) + fmaf(q0, w2v.x, Bv0);
        float y01 = bf2f_hi(ap0.x) + fmaf(q0, w2v.y, Bv1);
        float y02 = bf2f_lo(ap0.y) + fmaf(q0, w2v.z, Bv2);
        float y03 = bf2f_hi(ap0.y) + fmaf(q0, w2v.w, Bv3);
        float acc0 = fmaxf(y00, 0.f) * wdv.x + fmaxf(y01, 0.f) * wdv.y
                   + fmaxf(y02, 0.f) * wdv.z + fmaxf(y03, 0.f) * wdv.w;
        float y10 = bf2f_lo(ap1.x) + fmaf(q1, w2v.x, Bv0);
        float y11 = bf2f_hi(ap1.x) + fmaf(q1, w2v.y, Bv1);
        float y12 = bf2f_lo(ap1.y) + fmaf(q1, w2v.z, Bv2);
        float y13 = bf2f_hi(ap1.y) + fmaf(q1, w2v.w, Bv3);
        float acc1 = fmaxf(y10, 0.f) * wdv.x + fmaxf(y11, 0.f) * wdv.y
                   + fmaxf(y12, 0.f) * wdv.z + fmaxf(y13, 0.f) * wdv.w;
        if (lane == 0) {
            acc0 = fmaf(fmaxf(t0 + fmaf(q0, w2_l, B_l), 0.f), wd_l, acc0);
            acc1 = fmaf(fmaxf(t1 + fmaf(q1, w2_l, B_l), 0.f), wd_l, acc1);
        }
#pragma unroll
        for (int off = 32; off > 0; off >>= 1) {
            acc0 += __shfl_xor(acc0, off, 64);
            acc1 += __shfl_xor(acc1, off, 64);
        }
        if (lane == 0) {
            out[(int)pk0.x] = acc0 + bd;
            out[(int)pk1.x] = acc1 + bd;
        }
    }
    if (i < end) {
        uint4 pk = epack[i];
        float q = __uint_as_float(pk.w);
        const uint* Ar = A16u + (size_t)pk.y * AB_U;
        uint2 ap = *(const uint2*)(Ar + lane * 2);
        float y0 = bf2f_lo(ap.x) + fmaf(q, w2v.x, Bv0);
        float y1 = bf2f_hi(ap.x) + fmaf(q, w2v.y, Bv1);
        float y2 = bf2f_lo(ap.y) + fmaf(q, w2v.z, Bv2);
        float y3 = bf2f_hi(ap.y) + fmaf(q, w2v.w, Bv3);
        float acc = fmaxf(y0, 0.f) * wdv.x + fmaxf(y1, 0.f) * wdv.y
                  + fmaxf(y2, 0.f) * wdv.z + fmaxf(y3, 0.f) * wdv.w;
        if (lane == 0) {
            float yl = bf2f_lo(Ar[128]) + fmaf(q, w2_l, B_l);
            acc = fmaf(fmaxf(yl, 0.f), wd_l, acc);
        }
#pragma unroll
        for (int off = 32; off > 0; off >>= 1) acc += __shfl_xor(acc, off, 64);
        if (lane == 0) out[(int)pk.x] = acc + bd;
    }
}

extern "C" void kernel_launch(void* const* d_in, const int* in_sizes, int n_in,
                              void* d_out, int out_size, void* d_ws, size_t ws_size,
                              hipStream_t stream) {
    (void)n_in; (void)out_size; (void)ws_size;
    const float* x   = (const float*)d_in[0];
    const float* ea  = (const float*)d_in[1];
    const float* qy  = (const float*)d_in[2];
    const int*   adj = (const int*)d_in[3];
    const float* t   = (const float*)d_in[4];
    // d_in[5]=num_steps (unused), d_in[6]=batch (unused)
    const float* We  = (const float*)d_in[7];
    const float* be  = (const float*)d_in[8];
    const float* Wo  = (const float*)d_in[9];
    const float* bo  = (const float*)d_in[10];
    const float* Wl1 = (const float*)d_in[11];
    const float* bl1 = (const float*)d_in[12];
    const float* Wn1 = (const float*)d_in[13];
    const float* bn1 = (const float*)d_in[14];
    const float* Wl2 = (const float*)d_in[15];
    const float* bl2 = (const float*)d_in[16];
    const float* Wn2 = (const float*)d_in[17];
    const float* bn2 = (const float*)d_in[18];
    const float* Wl3 = (const float*)d_in[19];
    const float* bl3 = (const float*)d_in[20];
    const float* Wn3 = (const float*)d_in[21];
    const float* bn3 = (const float*)d_in[22];
    const float* Wt1 = (const float*)d_in[23];
    const float* bt1 = (const float*)d_in[24];
    const float* Wt2 = (const float*)d_in[25];
    const float* bt2 = (const float*)d_in[26];
    const float* Wd1 = (const float*)d_in[27];
    const float* bd1 = (const float*)d_in[28];
    const float* Wd2 = (const float*)d_in[29];
    const float* bd2 = (const float*)d_in[30];
    float* out = (float*)d_out;

    int N = in_sizes[0];
    int E = in_sizes[3] / 2;
    const int* src = adj;
    const int* dst = adj + E;

    float* w    = (float*)d_ws;
    float* temb = w;            // wsmall block (1024 floats)
    float* P2   = w + 128;
    float* Q2   = w + 256;
    float* R2   = w + 384;
    float* P3   = w + 512;
    float* Q3   = w + 640;
    float* R3   = w + 768;
    float* scal = w + 896;
    float* h    = w + 1024;                         // N*128 f32
    float* agg  = h + (size_t)N * 128;              // N*128 f32 (first N = agg1)
    uint*  h16u = (uint*)(agg + (size_t)N * 128);   // N*64 uints (bf16 pairs)
    uint*  A16u = h16u + (size_t)N * 64;            // N*AB_U uints
    uint*  B16u = A16u + (size_t)N * AB_U;          // N*AB_U uints
    int* rowstart = (int*)(B16u + (size_t)N * AB_U);  // N+1
    int* cursor   = rowstart + (N + 1);               // N (hist cnt / scatter cursor)
    int* partials = cursor + N;                       // scan partials
    int nblk = (N + 1023) / 1024;
    char* pcur = (char*)(partials + nblk + 1);
    pcur = (char*)(((uintptr_t)pcur + 15) & ~(uintptr_t)15);
    uint4* epack = (uint4*)pcur;                      // E * 16B
    uint* Wt16u = (uint*)(epack + E);                 // 512*64 uints (bf16 Wd1^T)

    // ---- CSR build (by dst) ----
    hipMemsetAsync(cursor, 0, (size_t)N * sizeof(int), stream);
    hist_kernel<<<(E + 255) / 256, 256, 0, stream>>>(dst, cursor, E);
    scan1_kernel<<<nblk, 256, 0, stream>>>(cursor, rowstart, partials, N);
    scan2_kernel<<<1, 64, 0, stream>>>(partials, rowstart, nblk, N);
    scan3_kernel<<<(N + 255) / 256, 256, 0, stream>>>(rowstart, partials, N);
    hipMemsetAsync(cursor, 0, (size_t)N * sizeof(int), stream);
    scatter_kernel<<<(E + 255) / 256, 256, 0, stream>>>(src, dst, ea, qy, rowstart, cursor, epack, E);

    wt16_kernel<<<512, 64, 0, stream>>>(Wd1, Wt16u);
    precompute_kernel<<<1, 256, 0, stream>>>(t, We, be, Wo, bo, Wl1, bl1,
                                             Wl2, bl2, Wl3, bl3,
                                             Wt1, bt1, Wt2, bt2, w);
    // layer 1
    edge1_kernel<<<(N + 255) / 256, 256, 0, stream>>>(x, epack, rowstart, scal, agg, N);
    node1_kernel<<<(N * 64 + 255) / 256, 256, 0, stream>>>(x, agg, Wn1, bn1, temb, h, h16u, N);
    // layer 2
    aggL_kernel<<<(N + 3) / 4, 256, 0, stream>>>(h16u, epack, rowstart, P2, Q2, R2, agg, N);
    nodeL_kernel<<<(N + 63) / 64, 256, 0, stream>>>(h, agg, Wn2, bn2, temb, h16u, N);
    // layer 3 (node update fused with decode A/B precompute, MFMA phase 2)
    aggL_kernel<<<(N + 3) / 4, 256, 0, stream>>>(h16u, epack, rowstart, P3, Q3, R3, agg, N);
    node3_decode_kernel<<<(N + 15) / 16, 256, 0, stream>>>(h, agg, Wn3, bn3, temb, Wt16u,
                                                           Wd1, bd1,
                                                           (ushort*)A16u, (ushort*)B16u, N);
    // decode edges
    decodeE_kernel<<<(N + 3) / 4, 256, 0, stream>>>(A16u, B16u, epack, rowstart, Wd1, Wd2, bd2, out, N);
}

// Round 11
// 530.719 us; speedup vs baseline: 1.1893x; 1.0806x over previous
//
#include <hip/hip_runtime.h>

typedef unsigned int uint;
typedef unsigned short ushort;

#define AB_U 132  // A/B row stride in uints (264 bf16 elems, 257 used)

typedef __attribute__((ext_vector_type(8))) short short8;
typedef __attribute__((ext_vector_type(4))) float f32x4;
union U4S8 { uint4 u; short8 s; };

__device__ __forceinline__ ushort f2bf(float f) {
    uint u = __float_as_uint(f);
    u += 0x7FFFu + ((u >> 16) & 1u);   // round-to-nearest-even
    return (ushort)(u >> 16);
}
__device__ __forceinline__ float bf2f_lo(uint p) { return __uint_as_float(p << 16); }
__device__ __forceinline__ float bf2f_hi(uint p) { return __uint_as_float(p & 0xFFFF0000u); }
__device__ __forceinline__ uint packbf(float lo, float hi) {
    return (uint)f2bf(lo) | ((uint)f2bf(hi) << 16);
}

// ---------------- precompute: temb MLP + rank-2 edge-lin factors ----------------
// wsmall layout (floats): temb[0:128] P2[128:256] Q2[256:384] R2[384:512]
//                         P3[512:640] Q3[640:768] R3[768:896] scal[896:899]
__global__ __launch_bounds__(256) void precompute_kernel(
    const float* __restrict__ t,
    const float* __restrict__ We, const float* __restrict__ be,
    const float* __restrict__ Wo, const float* __restrict__ bo,
    const float* __restrict__ Wl1, const float* __restrict__ bl1,
    const float* __restrict__ Wl2, const float* __restrict__ bl2,
    const float* __restrict__ Wl3, const float* __restrict__ bl3,
    const float* __restrict__ Wt1, const float* __restrict__ bt1,
    const float* __restrict__ Wt2, const float* __restrict__ bt2,
    float* __restrict__ wsmall)
{
    __shared__ float t0[128];
    __shared__ float y1[256];
    int tid = threadIdx.x;
    float tt = t[0] * 4.0f;
    if (tid < 64) {
        float f = expf(-logf(10000.0f) * (float)tid / 63.0f);
        float v = tt * f;
        t0[tid]      = sinf(v);
        t0[tid + 64] = cosf(v);
    }
    __syncthreads();
    {
        float acc = bt1[tid];
        for (int k = 0; k < 128; k++) acc = fmaf(t0[k], Wt1[k * 256 + tid], acc);
        y1[tid] = fmaxf(acc, 0.0f);
    }
    __syncthreads();
    if (tid < 128) {
        float a = bt2[tid];
        for (int k = 0; k < 256; k++) a = fmaf(y1[k], Wt2[k * 128 + tid], a);
        wsmall[tid] = a;  // temb
    }
    {
        int j = tid & 127;
        const float* Wl  = (tid < 128) ? Wl2 : Wl3;
        const float* blp = (tid < 128) ? bl2 : bl3;
        float p = 0.f, q = 0.f, r = blp[j];
        for (int k = 0; k < 64; k++) {
            float w1 = Wl[k * 128 + j], w2 = Wl[(64 + k) * 128 + j];
            p = fmaf(We[k], w1, p);
            q = fmaf(Wo[k], w2, q);
            r = fmaf(be[k], w1, r);
            r = fmaf(bo[k], w2, r);
        }
        int base = (tid < 128) ? 128 : 512;
        wsmall[base + j]       = p;
        wsmall[base + 128 + j] = q;
        wsmall[base + 256 + j] = r;
    }
    if (tid == 0) {
        float p1 = 0.f, q1 = 0.f, r1 = bl1[0];
        for (int k = 0; k < 64; k++) {
            p1 = fmaf(We[k], Wl1[k], p1);
            q1 = fmaf(Wo[k], Wl1[64 + k], q1);
            r1 = fmaf(be[k], Wl1[k], r1);
            r1 = fmaf(bo[k], Wl1[64 + k], r1);
        }
        wsmall[896] = p1; wsmall[897] = q1; wsmall[898] = r1;
    }
}

// stage Wd1 columns as bf16, transposed: Wt16u[c][k-pairs], c in [0,512)
__global__ __launch_bounds__(64) void wt16_kernel(
    const float* __restrict__ Wd1, uint* __restrict__ Wt16u)
{
    int c = blockIdx.x;      // 0..511
    int u = threadIdx.x;     // 0..63 (k-pair)
    int k = u * 2;
    float lo, hi;
    if (c < 256) {
        lo = Wd1[k * 257 + c];
        hi = Wd1[(k + 1) * 257 + c];
    } else {
        int cc = c - 256;
        lo = Wd1[(128 + k) * 257 + cc];
        hi = Wd1[(128 + k + 1) * 257 + cc];
    }
    Wt16u[c * 64 + u] = packbf(lo, hi);
}

// stage a 128x128 row-major (k-major) weight as bf16 transposed: Wt[c][k-pairs]
__global__ __launch_bounds__(64) void wnt16_kernel(
    const float* __restrict__ W, uint* __restrict__ Wt)
{
    int c = blockIdx.x, u = threadIdx.x;
    Wt[c * 64 + u] = packbf(W[(2 * u) * 128 + c], W[(2 * u + 1) * 128 + c]);
}

// ---------------- CSR build: histogram -> hierarchical scan -> scatter ----------------
__global__ __launch_bounds__(256) void hist_kernel(
    const int* __restrict__ dst, int* __restrict__ cnt, int E)
{
    int e = blockIdx.x * blockDim.x + threadIdx.x;
    if (e < E) atomicAdd(&cnt[dst[e]], 1);
}

__global__ __launch_bounds__(256) void scan1_kernel(
    const int* __restrict__ cnt, int* __restrict__ rowstart,
    int* __restrict__ partials, int N)
{
    __shared__ int wsum[4];
    int b = blockIdx.x;
    int tid = threadIdx.x, lane = tid & 63, w = tid >> 6;
    int i0 = b * 1024 + tid * 4;
    int v0 = (i0     < N) ? cnt[i0]     : 0;
    int v1 = (i0 + 1 < N) ? cnt[i0 + 1] : 0;
    int v2 = (i0 + 2 < N) ? cnt[i0 + 2] : 0;
    int v3 = (i0 + 3 < N) ? cnt[i0 + 3] : 0;
    int tsum = v0 + v1 + v2 + v3;
    int s = tsum;
#pragma unroll
    for (int off = 1; off < 64; off <<= 1) {
        int u = __shfl_up(s, off, 64);
        if (lane >= off) s += u;
    }
    if (lane == 63) wsum[w] = s;
    __syncthreads();
    int woff = 0;
    for (int k = 0; k < w; k++) woff += wsum[k];
    int ex = woff + s - tsum;
    if (i0     < N) rowstart[i0]     = ex;
    if (i0 + 1 < N) rowstart[i0 + 1] = ex + v0;
    if (i0 + 2 < N) rowstart[i0 + 2] = ex + v0 + v1;
    if (i0 + 3 < N) rowstart[i0 + 3] = ex + v0 + v1 + v2;
    if (tid == 255) partials[b] = woff + s;
}

__global__ __launch_bounds__(64) void scan2_kernel(
    int* __restrict__ partials, int* __restrict__ rowstart, int nblk, int N)
{
    int lane = threadIdx.x;
    int carry = 0;
    for (int base = 0; base < nblk; base += 64) {
        int i = base + lane;
        int v = (i < nblk) ? partials[i] : 0;
        int s = v;
#pragma unroll
        for (int off = 1; off < 64; off <<= 1) {
            int u = __shfl_up(s, off, 64);
            if (lane >= off) s += u;
        }
        if (i < nblk) partials[i] = carry + s - v;
        carry += __shfl(s, 63, 64);
    }
    if (lane == 0) rowstart[N] = carry;
}

__global__ __launch_bounds__(256) void scan3_kernel(
    int* __restrict__ rowstart, const int* __restrict__ partials, int N)
{
    int i = blockIdx.x * blockDim.x + threadIdx.x;
    if (i < N) rowstart[i] += partials[i >> 10];
}

__global__ __launch_bounds__(256) void scatter_kernel(
    const int* __restrict__ src, const int* __restrict__ dst,
    const float* __restrict__ ea, const float* __restrict__ qy,
    const int* __restrict__ rowstart, int* __restrict__ cursor,
    uint4* __restrict__ epack, int E)
{
    int e = blockIdx.x * blockDim.x + threadIdx.x;
    if (e >= E) return;
    int d = dst[e];
    int pos = atomicAdd(&cursor[d], 1);
    uint4 pk;
    pk.x = (uint)e;
    pk.y = (uint)src[e];
    pk.z = __float_as_uint(ea[e]);
    pk.w = __float_as_uint(qy[e]);
    epack[rowstart[d] + pos] = pk;
}

// ---------------- layer 1 (scalar channel), pull over CSR, unroll 2 ----------------
__global__ __launch_bounds__(256) void edge1_kernel(
    const float* __restrict__ x, const uint4* __restrict__ epack,
    const int* __restrict__ rowstart, const float* __restrict__ scal,
    float* __restrict__ agg1, int N)
{
    int v = blockIdx.x * blockDim.x + threadIdx.x;
    if (v >= N) return;
    float s0 = scal[0], s1 = scal[1], s2 = scal[2];
    int beg = rowstart[v], end = rowstart[v + 1];
    float m = 0.0f;
    int i = beg;
    for (; i + 2 <= end; i += 2) {
        uint4 pk0 = epack[i];
        uint4 pk1 = epack[i + 1];
        float x0 = x[(int)pk0.y];
        float x1 = x[(int)pk1.y];
        m += fmaxf(x0 + fmaf(__uint_as_float(pk0.z), s0, fmaf(__uint_as_float(pk0.w), s1, s2)), 0.0f);
        m += fmaxf(x1 + fmaf(__uint_as_float(pk1.z), s0, fmaf(__uint_as_float(pk1.w), s1, s2)), 0.0f);
    }
    if (i < end) {
        uint4 pk = epack[i];
        m += fmaxf(x[(int)pk.y] + fmaf(__uint_as_float(pk.z), s0, fmaf(__uint_as_float(pk.w), s1, s2)), 0.0f);
    }
    agg1[v] = m;
}

// h1 = (x+agg1)*Wn1 + bn1 + temb -> bf16 shadow only
__global__ __launch_bounds__(256) void node1_kernel(
    const float* __restrict__ x, const float* __restrict__ agg1,
    const float* __restrict__ Wn1, const float* __restrict__ bn1,
    const float* __restrict__ temb, uint* __restrict__ h16u, int N)
{
    int i = blockIdx.x * blockDim.x + threadIdx.x;  // N*64 threads
    int n = i >> 6, j2 = (i & 63) * 2;
    if (n >= N) return;
    float v = x[n] + agg1[n];
    float h0 = fmaf(v, Wn1[j2],     bn1[j2]     + temb[j2]);
    float h1 = fmaf(v, Wn1[j2 + 1], bn1[j2 + 1] + temb[j2 + 1]);
    h16u[(size_t)n * 64 + (j2 >> 1)] = packbf(h0, h1);
}

// ------------ layers 2/3: pull aggregation (bf16 h gather), unroll 4, bf16 agg out --
__global__ __launch_bounds__(256) void aggL_kernel(
    const uint* __restrict__ h16u, const uint4* __restrict__ epack,
    const int* __restrict__ rowstart,
    const float* __restrict__ P, const float* __restrict__ Q,
    const float* __restrict__ R, uint* __restrict__ agg16u, int N)
{
    int v = blockIdx.x * 4 + (threadIdx.x >> 6);
    int lane = threadIdx.x & 63;
    if (v >= N) return;
    int c = lane * 2;
    float2 Pv = *(const float2*)(P + c);
    float2 Qv = *(const float2*)(Q + c);
    float2 Rv = *(const float2*)(R + c);
    int beg = rowstart[v], end = rowstart[v + 1];
    float accx = 0.0f, accy = 0.0f;
    int i = beg;
    for (; i + 4 <= end; i += 4) {
        uint4 pk0 = epack[i];
        uint4 pk1 = epack[i + 1];
        uint4 pk2 = epack[i + 2];
        uint4 pk3 = epack[i + 3];
        uint hp0 = h16u[(size_t)pk0.y * 64 + lane];
        uint hp1 = h16u[(size_t)pk1.y * 64 + lane];
        uint hp2 = h16u[(size_t)pk2.y * 64 + lane];
        uint hp3 = h16u[(size_t)pk3.y * 64 + lane];
        float a0 = __uint_as_float(pk0.z), b0 = __uint_as_float(pk0.w);
        float a1 = __uint_as_float(pk1.z), b1 = __uint_as_float(pk1.w);
        float a2 = __uint_as_float(pk2.z), b2 = __uint_as_float(pk2.w);
        float a3 = __uint_as_float(pk3.z), b3 = __uint_as_float(pk3.w);
        accx += fmaxf(bf2f_lo(hp0) + fmaf(a0, Pv.x, fmaf(b0, Qv.x, Rv.x)), 0.0f);
        accy += fmaxf(bf2f_hi(hp0) + fmaf(a0, Pv.y, fmaf(b0, Qv.y, Rv.y)), 0.0f);
        accx += fmaxf(bf2f_lo(hp1) + fmaf(a1, Pv.x, fmaf(b1, Qv.x, Rv.x)), 0.0f);
        accy += fmaxf(bf2f_hi(hp1) + fmaf(a1, Pv.y, fmaf(b1, Qv.y, Rv.y)), 0.0f);
        accx += fmaxf(bf2f_lo(hp2) + fmaf(a2, Pv.x, fmaf(b2, Qv.x, Rv.x)), 0.0f);
        accy += fmaxf(bf2f_hi(hp2) + fmaf(a2, Pv.y, fmaf(b2, Qv.y, Rv.y)), 0.0f);
        accx += fmaxf(bf2f_lo(hp3) + fmaf(a3, Pv.x, fmaf(b3, Qv.x, Rv.x)), 0.0f);
        accy += fmaxf(bf2f_hi(hp3) + fmaf(a3, Pv.y, fmaf(b3, Qv.y, Rv.y)), 0.0f);
    }
    for (; i < end; i++) {
        uint4 pk = epack[i];
        float a = __uint_as_float(pk.z), b = __uint_as_float(pk.w);
        uint hp = h16u[(size_t)pk.y * 64 + lane];
        accx += fmaxf(bf2f_lo(hp) + fmaf(a, Pv.x, fmaf(b, Qv.x, Rv.x)), 0.0f);
        accy += fmaxf(bf2f_hi(hp) + fmaf(a, Pv.y, fmaf(b, Qv.y, Rv.y)), 0.0f);
    }
    agg16u[(size_t)v * 64 + lane] = packbf(accx, accy);
}

// ----- layer 2 node update via MFMA: 64 nodes/block, wave = 16-row tile x 8 col-tiles
__global__ __launch_bounds__(256) void nodeL_kernel(
    const uint* __restrict__ agg16u, const uint* __restrict__ Wn2t16u,
    const float* __restrict__ bn, const float* __restrict__ temb,
    uint* __restrict__ h16u, int N)
{
    __shared__ uint vs16[64][68];   // (h+agg) bf16 pairs, 17.4 KB
    int nb = blockIdx.x * 64;
    int tid = threadIdx.x;
    for (int idx = tid; idx < 64 * 32; idx += 256) {   // uint2 per idx
        int n = idx >> 5, u2 = (idx & 31) * 2;
        uint2 pk = make_uint2(0, 0);
        if (nb + n < N) {
            uint2 hp = *(const uint2*)(h16u + (size_t)(nb + n) * 64 + u2);
            uint2 gp = *(const uint2*)(agg16u + (size_t)(nb + n) * 64 + u2);
            pk.x = packbf(bf2f_lo(hp.x) + bf2f_lo(gp.x), bf2f_hi(hp.x) + bf2f_hi(gp.x));
            pk.y = packbf(bf2f_lo(hp.y) + bf2f_lo(gp.y), bf2f_hi(hp.y) + bf2f_hi(gp.y));
        }
        *(uint2*)(&vs16[n][u2]) = pk;
    }
    __syncthreads();
    int wv = tid >> 6, lane = tid & 63, cl = lane & 15, g = lane >> 4;
    int rbase = wv * 16;
    short8 afr[4];
#pragma unroll
    for (int kc = 0; kc < 4; kc++) {
        U4S8 t;
        t.u = *(const uint4*)(&vs16[rbase + cl][kc * 16 + g * 4]);
        afr[kc] = t.s;
    }
#pragma unroll
    for (int tt = 0; tt < 8; tt++) {
        int c = tt * 16 + cl;
        float bias = bn[c] + temb[c];
        f32x4 acc = {bias, bias, bias, bias};
#pragma unroll
        for (int kc = 0; kc < 4; kc++) {
            U4S8 t;
            t.u = *(const uint4*)(Wn2t16u + (size_t)c * 64 + kc * 16 + g * 4);
            acc = __builtin_amdgcn_mfma_f32_16x16x32_bf16(afr[kc], t.s, acc, 0, 0, 0);
        }
#pragma unroll
        for (int r = 0; r < 4; r++) {
            int n = nb + rbase + g * 4 + r;
            float val = acc[r];
            float nbr = __shfl_down(val, 1, 64);
            if (n < N && (cl & 1) == 0)
                h16u[(size_t)n * 64 + (c >> 1)] = packbf(val, nbr);
        }
    }
}

// ------- fused layer-3 node update + decode A/B precompute, all-MFMA -------
__global__ __launch_bounds__(256) void node3_decode_kernel(
    const uint* __restrict__ h16u, const uint* __restrict__ agg16u,
    const uint* __restrict__ Wn3t16u, const float* __restrict__ bn3,
    const float* __restrict__ temb, const uint* __restrict__ Wt16u,
    const float* __restrict__ Wd1, const float* __restrict__ bd1,
    ushort* __restrict__ A16s, ushort* __restrict__ B16s, int N)
{
    __shared__ uint vs16[16][68];    // (h+agg) bf16 pairs, 4.35 KB
    __shared__ float hs3[16][132];   // h3 f32, 8.45 KB
    int nb = blockIdx.x * 16;
    int tid = threadIdx.x;
    for (int idx = tid; idx < 16 * 32; idx += 256) {   // uint2 per idx
        int n = idx >> 5, u2 = (idx & 31) * 2;
        uint2 pk = make_uint2(0, 0);
        if (nb + n < N) {
            uint2 hp = *(const uint2*)(h16u + (size_t)(nb + n) * 64 + u2);
            uint2 gp = *(const uint2*)(agg16u + (size_t)(nb + n) * 64 + u2);
            pk.x = packbf(bf2f_lo(hp.x) + bf2f_lo(gp.x), bf2f_hi(hp.x) + bf2f_hi(gp.x));
            pk.y = packbf(bf2f_lo(hp.y) + bf2f_lo(gp.y), bf2f_hi(hp.y) + bf2f_hi(gp.y));
        }
        *(uint2*)(&vs16[n][u2]) = pk;
    }
    __syncthreads();
    int wv = tid >> 6, lane = tid & 63, cl = lane & 15, g = lane >> 4;
    // phase 1 (MFMA): h3(16x128) = vs(16x128) @ Wn3(128x128) + bn3 + temb -> hs3 f32
    {
        short8 afr[4];
#pragma unroll
        for (int kc = 0; kc < 4; kc++) {
            U4S8 t;
            t.u = *(const uint4*)(&vs16[cl][kc * 16 + g * 4]);
            afr[kc] = t.s;
        }
#pragma unroll
        for (int tt = 0; tt < 2; tt++) {
            int c = wv * 32 + tt * 16 + cl;
            float bias = bn3[c] + temb[c];
            f32x4 acc = {bias, bias, bias, bias};
#pragma unroll
            for (int kc = 0; kc < 4; kc++) {
                U4S8 t;
                t.u = *(const uint4*)(Wn3t16u + (size_t)c * 64 + kc * 16 + g * 4);
                acc = __builtin_amdgcn_mfma_f32_16x16x32_bf16(afr[kc], t.s, acc, 0, 0, 0);
            }
#pragma unroll
            for (int r = 0; r < 4; r++) hs3[g * 4 + r][c] = acc[r];
        }
    }
    __syncthreads();
    // phase 2 (MFMA): [A|B](16x512) = h3 @ Wt16 ; pack A-frags from hs3 f32
    {
        short8 afr[4];
#pragma unroll
        for (int kc = 0; kc < 4; kc++) {
            float4 lo = *(const float4*)(&hs3[cl][kc * 32 + g * 8]);
            float4 hi = *(const float4*)(&hs3[cl][kc * 32 + g * 8 + 4]);
            U4S8 t;
            t.u.x = packbf(lo.x, lo.y);
            t.u.y = packbf(lo.z, lo.w);
            t.u.z = packbf(hi.x, hi.y);
            t.u.w = packbf(hi.z, hi.w);
            afr[kc] = t.s;
        }
#pragma unroll
        for (int tt = 0; tt < 8; tt++) {
            int tile = wv * 8 + tt;
            int c = tile * 16 + cl;            // combined col 0..511
            float bias = (tile < 16) ? bd1[c] : 0.0f;
            f32x4 acc = {bias, bias, bias, bias};
#pragma unroll
            for (int kc = 0; kc < 4; kc++) {
                U4S8 t;
                t.u = *(const uint4*)(Wt16u + (size_t)c * 64 + kc * 16 + g * 4);
                acc = __builtin_amdgcn_mfma_f32_16x16x32_bf16(afr[kc], t.s, acc, 0, 0, 0);
            }
            ushort* OUT = (tile < 16) ? A16s : B16s;
            int oc = (tile < 16) ? c : (c - 256);
#pragma unroll
            for (int r = 0; r < 4; r++) {
                int n = nb + g * 4 + r;
                if (n < N) OUT[(size_t)n * 264 + oc] = f2bf(acc[r]);
            }
        }
    }
    // tail: o = 256 column, 4 lanes per node + shfl reduce
    if (tid < 64) {
        int n = tid >> 2, j = tid & 3;
        float sA = 0.f, sB = 0.f;
        for (int k = j * 32; k < j * 32 + 32; k++) {
            float hv = hs3[n][k];
            sA = fmaf(hv, Wd1[k * 257 + 256], sA);
            sB = fmaf(hv, Wd1[(128 + k) * 257 + 256], sB);
        }
        sA += __shfl_xor(sA, 1, 64);
        sA += __shfl_xor(sA, 2, 64);
        sB += __shfl_xor(sB, 1, 64);
        sB += __shfl_xor(sB, 2, 64);
        if (j == 0 && nb + n < N) {
            A16s[(size_t)(nb + n) * 264 + 256] = f2bf(sA + bd1[256]);
            B16s[(size_t)(nb + n) * 264 + 256] = f2bf(sB);
        }
    }
}

// ---- decode edges, dst-grouped: wave per node, bf16 A gather, B in regs, unroll 2 ----
__global__ __launch_bounds__(256) void decodeE_kernel(
    const uint* __restrict__ A16u, const uint* __restrict__ B16u,
    const uint4* __restrict__ epack, const int* __restrict__ rowstart,
    const float* __restrict__ Wd1, const float* __restrict__ Wd2,
    const float* __restrict__ bd2, float* __restrict__ out, int N)
{
    int v = blockIdx.x * 4 + (threadIdx.x >> 6);
    int lane = threadIdx.x & 63;
    if (v >= N) return;
    const float* w256 = Wd1 + 256 * 257;
    float4 w2v = *(const float4*)(w256 + lane * 4);
    float4 wdv = *(const float4*)(Wd2 + lane * 4);
    const uint* Br = B16u + (size_t)v * AB_U;
    uint2 bp = *(const uint2*)(Br + lane * 2);
    float Bv0 = bf2f_lo(bp.x), Bv1 = bf2f_hi(bp.x);
    float Bv2 = bf2f_lo(bp.y), Bv3 = bf2f_hi(bp.y);
    float w2_l = w256[256], wd_l = Wd2[256], bd = bd2[0];
    float B_l = bf2f_lo(Br[128]);
    int beg = rowstart[v], end = rowstart[v + 1];
    int i = beg;
    for (; i + 2 <= end; i += 2) {
        uint4 pk0 = epack[i];
        uint4 pk1 = epack[i + 1];
        float q0 = __uint_as_float(pk0.w);
        float q1 = __uint_as_float(pk1.w);
        const uint* Ar0 = A16u + (size_t)pk0.y * AB_U;
        const uint* Ar1 = A16u + (size_t)pk1.y * AB_U;
        uint2 ap0 = *(const uint2*)(Ar0 + lane * 2);
        uint2 ap1 = *(const uint2*)(Ar1 + lane * 2);
        float t0 = 0.f, t1 = 0.f;
        if (lane == 0) {
            t0 = bf2f_lo(Ar0[128]);
            t1 = bf2f_lo(Ar1[128]);
        }
        float y00 = bf2f_lo(ap0.x) + fmaf(q0, w2v.x, Bv0);
        float y01 = bf2f_hi(ap0.x) + fmaf(q0, w2v.y, Bv1);
        float y02 = bf2f_lo(ap0.y) + fmaf(q0, w2v.z, Bv2);
        float y03 = bf2f_hi(ap0.y) + fmaf(q0, w2v.w, Bv3);
        float acc0 = fmaxf(y00, 0.f) * wdv.x + fmaxf(y01, 0.f) * wdv.y
                   + fmaxf(y02, 0.f) * wdv.z + fmaxf(y03, 0.f) * wdv.w;
        float y10 = bf2f_lo(ap1.x) + fmaf(q1, w2v.x, Bv0);
        float y11 = bf2f_hi(ap1.x) + fmaf(q1, w2v.y, Bv1);
        float y12 = bf2f_lo(ap1.y) + fmaf(q1, w2v.z, Bv2);
        float y13 = bf2f_hi(ap1.y) + fmaf(q1, w2v.w, Bv3);
        float acc1 = fmaxf(y10, 0.f) * wdv.x + fmaxf(y11, 0.f) * wdv.y
                   + fmaxf(y12, 0.f) * wdv.z + fmaxf(y13, 0.f) * wdv.w;
        if (lane == 0) {
            acc0 = fmaf(fmaxf(t0 + fmaf(q0, w2_l, B_l), 0.f), wd_l, acc0);
            acc1 = fmaf(fmaxf(t1 + fmaf(q1, w2_l, B_l), 0.f), wd_l, acc1);
        }
#pragma unroll
        for (int off = 32; off > 0; off >>= 1) {
            acc0 += __shfl_xor(acc0, off, 64);
            acc1 += __shfl_xor(acc1, off, 64);
        }
        if (lane == 0) {
            out[(int)pk0.x] = acc0 + bd;
            out[(int)pk1.x] = acc1 + bd;
        }
    }
    if (i < end) {
        uint4 pk = epack[i];
        float q = __uint_as_float(pk.w);
        const uint* Ar = A16u + (size_t)pk.y * AB_U;
        uint2 ap = *(const uint2*)(Ar + lane * 2);
        float y0 = bf2f_lo(ap.x) + fmaf(q, w2v.x, Bv0);
        float y1 = bf2f_hi(ap.x) + fmaf(q, w2v.y, Bv1);
        float y2 = bf2f_lo(ap.y) + fmaf(q, w2v.z, Bv2);
        float y3 = bf2f_hi(ap.y) + fmaf(q, w2v.w, Bv3);
        float acc = fmaxf(y0, 0.f) * wdv.x + fmaxf(y1, 0.f) * wdv.y
                  + fmaxf(y2, 0.f) * wdv.z + fmaxf(y3, 0.f) * wdv.w;
        if (lane == 0) {
            float yl = bf2f_lo(Ar[128]) + fmaf(q, w2_l, B_l);
            acc = fmaf(fmaxf(yl, 0.f), wd_l, acc);
        }
#pragma unroll
        for (int off = 32; off > 0; off >>= 1) acc += __shfl_xor(acc, off, 64);
        if (lane == 0) out[(int)pk.x] = acc + bd;
    }
}

extern "C" void kernel_launch(void* const* d_in, const int* in_sizes, int n_in,
                              void* d_out, int out_size, void* d_ws, size_t ws_size,
                              hipStream_t stream) {
    (void)n_in; (void)out_size; (void)ws_size;
    const float* x   = (const float*)d_in[0];
    const float* ea  = (const float*)d_in[1];
    const float* qy  = (const float*)d_in[2];
    const int*   adj = (const int*)d_in[3];
    const float* t   = (const float*)d_in[4];
    // d_in[5]=num_steps (unused), d_in[6]=batch (unused)
    const float* We  = (const float*)d_in[7];
    const float* be  = (const float*)d_in[8];
    const float* Wo  = (const float*)d_in[9];
    const float* bo  = (const float*)d_in[10];
    const float* Wl1 = (const float*)d_in[11];
    const float* bl1 = (const float*)d_in[12];
    const float* Wn1 = (const float*)d_in[13];
    const float* bn1 = (const float*)d_in[14];
    const float* Wl2 = (const float*)d_in[15];
    const float* bl2 = (const float*)d_in[16];
    const float* Wn2 = (const float*)d_in[17];
    const float* bn2 = (const float*)d_in[18];
    const float* Wl3 = (const float*)d_in[19];
    const float* bl3 = (const float*)d_in[20];
    const float* Wn3 = (const float*)d_in[21];
    const float* bn3 = (const float*)d_in[22];
    const float* Wt1 = (const float*)d_in[23];
    const float* bt1 = (const float*)d_in[24];
    const float* Wt2 = (const float*)d_in[25];
    const float* bt2 = (const float*)d_in[26];
    const float* Wd1 = (const float*)d_in[27];
    const float* bd1 = (const float*)d_in[28];
    const float* Wd2 = (const float*)d_in[29];
    const float* bd2 = (const float*)d_in[30];
    float* out = (float*)d_out;

    int N = in_sizes[0];
    int E = in_sizes[3] / 2;
    const int* src = adj;
    const int* dst = adj + E;

    float* w    = (float*)d_ws;
    float* temb = w;            // wsmall block (1024 floats)
    float* P2   = w + 128;
    float* Q2   = w + 256;
    float* R2   = w + 384;
    float* P3   = w + 512;
    float* Q3   = w + 640;
    float* R3   = w + 768;
    float* scal = w + 896;
    float* agg1 = w + 1024;                          // N f32 (layer-1 scalar agg)
    uint*  h16u   = (uint*)(agg1 + N);               // N*64 uints (bf16 pairs)
    uint*  agg16u = h16u + (size_t)N * 64;           // N*64 uints (bf16 pairs)
    uint*  A16u   = agg16u + (size_t)N * 64;         // N*AB_U uints
    uint*  B16u   = A16u + (size_t)N * AB_U;         // N*AB_U uints
    int* rowstart = (int*)(B16u + (size_t)N * AB_U); // N+1
    int* cursor   = rowstart + (N + 1);              // N
    int* partials = cursor + N;
    int nblk = (N + 1023) / 1024;
    char* pcur = (char*)(partials + nblk + 1);
    pcur = (char*)(((uintptr_t)pcur + 15) & ~(uintptr_t)15);
    uint4* epack = (uint4*)pcur;                     // E * 16B
    uint* Wt16u   = (uint*)(epack + E);              // 512*64 uints (bf16 Wd1^T)
    uint* Wn2t16u = Wt16u + 512 * 64;                // 128*64 uints
    uint* Wn3t16u = Wn2t16u + 128 * 64;              // 128*64 uints

    // ---- CSR build (by dst) ----
    hipMemsetAsync(cursor, 0, (size_t)N * sizeof(int), stream);
    hist_kernel<<<(E + 255) / 256, 256, 0, stream>>>(dst, cursor, E);
    scan1_kernel<<<nblk, 256, 0, stream>>>(cursor, rowstart, partials, N);
    scan2_kernel<<<1, 64, 0, stream>>>(partials, rowstart, nblk, N);
    scan3_kernel<<<(N + 255) / 256, 256, 0, stream>>>(rowstart, partials, N);
    hipMemsetAsync(cursor, 0, (size_t)N * sizeof(int), stream);
    scatter_kernel<<<(E + 255) / 256, 256, 0, stream>>>(src, dst, ea, qy, rowstart, cursor, epack, E);

    wt16_kernel<<<512, 64, 0, stream>>>(Wd1, Wt16u);
    wnt16_kernel<<<128, 64, 0, stream>>>(Wn2, Wn2t16u);
    wnt16_kernel<<<128, 64, 0, stream>>>(Wn3, Wn3t16u);
    precompute_kernel<<<1, 256, 0, stream>>>(t, We, be, Wo, bo, Wl1, bl1,
                                             Wl2, bl2, Wl3, bl3,
                                             Wt1, bt1, Wt2, bt2, w);
    // layer 1
    edge1_kernel<<<(N + 255) / 256, 256, 0, stream>>>(x, epack, rowstart, scal, agg1, N);
    node1_kernel<<<(N * 64 + 255) / 256, 256, 0, stream>>>(x, agg1, Wn1, bn1, temb, h16u, N);
    // layer 2
    aggL_kernel<<<(N + 3) / 4, 256, 0, stream>>>(h16u, epack, rowstart, P2, Q2, R2, agg16u, N);
    nodeL_kernel<<<(N + 63) / 64, 256, 0, stream>>>(agg16u, Wn2t16u, bn2, temb, h16u, N);
    // layer 3 (node update fused with decode A/B precompute, all-MFMA)
    aggL_kernel<<<(N + 3) / 4, 256, 0, stream>>>(h16u, epack, rowstart, P3, Q3, R3, agg16u, N);
    node3_decode_kernel<<<(N + 15) / 16, 256, 0, stream>>>(h16u, agg16u, Wn3t16u, bn3, temb,
                                                           Wt16u, Wd1, bd1,
                                                           (ushort*)A16u, (ushort*)B16u, N);
    // decode edges
    decodeE_kernel<<<(N + 3) / 4, 256, 0, stream>>>(A16u, B16u, epack, rowstart, Wd1, Wd2, bd2, out, N);
}

// Round 12
// 517.271 us; speedup vs baseline: 1.2202x; 1.0260x over previous
//
#include <hip/hip_runtime.h>

typedef unsigned int uint;
typedef unsigned short ushort;

#define AB_U 132  // A/B row stride in uints (264 bf16 elems, 257 used)

typedef __attribute__((ext_vector_type(8))) short short8;
typedef __attribute__((ext_vector_type(4))) float f32x4;
union U4S8 { uint4 u; short8 s; };

__device__ __forceinline__ ushort f2bf(float f) {
    uint u = __float_as_uint(f);
    u += 0x7FFFu + ((u >> 16) & 1u);   // round-to-nearest-even
    return (ushort)(u >> 16);
}
__device__ __forceinline__ float bf2f_lo(uint p) { return __uint_as_float(p << 16); }
__device__ __forceinline__ float bf2f_hi(uint p) { return __uint_as_float(p & 0xFFFF0000u); }
__device__ __forceinline__ uint packbf(float lo, float hi) {
    return (uint)f2bf(lo) | ((uint)f2bf(hi) << 16);
}

// ---------------- precompute: temb MLP + rank-2 edge-lin factors ----------------
__global__ __launch_bounds__(256) void precompute_kernel(
    const float* __restrict__ t,
    const float* __restrict__ We, const float* __restrict__ be,
    const float* __restrict__ Wo, const float* __restrict__ bo,
    const float* __restrict__ Wl1, const float* __restrict__ bl1,
    const float* __restrict__ Wl2, const float* __restrict__ bl2,
    const float* __restrict__ Wl3, const float* __restrict__ bl3,
    const float* __restrict__ Wt1, const float* __restrict__ bt1,
    const float* __restrict__ Wt2, const float* __restrict__ bt2,
    float* __restrict__ wsmall)
{
    __shared__ float t0[128];
    __shared__ float y1[256];
    int tid = threadIdx.x;
    float tt = t[0] * 4.0f;
    if (tid < 64) {
        float f = expf(-logf(10000.0f) * (float)tid / 63.0f);
        float v = tt * f;
        t0[tid]      = sinf(v);
        t0[tid + 64] = cosf(v);
    }
    __syncthreads();
    {
        float acc = bt1[tid];
        for (int k = 0; k < 128; k++) acc = fmaf(t0[k], Wt1[k * 256 + tid], acc);
        y1[tid] = fmaxf(acc, 0.0f);
    }
    __syncthreads();
    if (tid < 128) {
        float a = bt2[tid];
        for (int k = 0; k < 256; k++) a = fmaf(y1[k], Wt2[k * 128 + tid], a);
        wsmall[tid] = a;  // temb
    }
    {
        int j = tid & 127;
        const float* Wl  = (tid < 128) ? Wl2 : Wl3;
        const float* blp = (tid < 128) ? bl2 : bl3;
        float p = 0.f, q = 0.f, r = blp[j];
        for (int k = 0; k < 64; k++) {
            float w1 = Wl[k * 128 + j], w2 = Wl[(64 + k) * 128 + j];
            p = fmaf(We[k], w1, p);
            q = fmaf(Wo[k], w2, q);
            r = fmaf(be[k], w1, r);
            r = fmaf(bo[k], w2, r);
        }
        int base = (tid < 128) ? 128 : 512;
        wsmall[base + j]       = p;
        wsmall[base + 128 + j] = q;
        wsmall[base + 256 + j] = r;
    }
    if (tid == 0) {
        float p1 = 0.f, q1 = 0.f, r1 = bl1[0];
        for (int k = 0; k < 64; k++) {
            p1 = fmaf(We[k], Wl1[k], p1);
            q1 = fmaf(Wo[k], Wl1[64 + k], q1);
            r1 = fmaf(be[k], Wl1[k], r1);
            r1 = fmaf(bo[k], Wl1[64 + k], r1);
        }
        wsmall[896] = p1; wsmall[897] = q1; wsmall[898] = r1;
    }
}

// stage Wd1 columns as bf16, transposed: Wt16u[c][k-pairs], c in [0,512)
__global__ __launch_bounds__(64) void wt16_kernel(
    const float* __restrict__ Wd1, uint* __restrict__ Wt16u)
{
    int c = blockIdx.x;      // 0..511
    int u = threadIdx.x;     // 0..63 (k-pair)
    int k = u * 2;
    float lo, hi;
    if (c < 256) {
        lo = Wd1[k * 257 + c];
        hi = Wd1[(k + 1) * 257 + c];
    } else {
        int cc = c - 256;
        lo = Wd1[(128 + k) * 257 + cc];
        hi = Wd1[(128 + k + 1) * 257 + cc];
    }
    Wt16u[c * 64 + u] = packbf(lo, hi);
}

// stage a 128x128 row-major (k-major) weight as bf16 transposed: Wt[c][k-pairs]
__global__ __launch_bounds__(64) void wnt16_kernel(
    const float* __restrict__ W, uint* __restrict__ Wt)
{
    int c = blockIdx.x, u = threadIdx.x;
    Wt[c * 64 + u] = packbf(W[(2 * u) * 128 + c], W[(2 * u + 1) * 128 + c]);
}

// ---------------- CSR build: histogram -> hierarchical scan -> scatter ----------------
__global__ __launch_bounds__(256) void hist_kernel(
    const int* __restrict__ dst, int* __restrict__ cnt, int E)
{
    int e = blockIdx.x * blockDim.x + threadIdx.x;
    if (e < E) atomicAdd(&cnt[dst[e]], 1);
}

__global__ __launch_bounds__(256) void scan1_kernel(
    const int* __restrict__ cnt, int* __restrict__ rowstart,
    int* __restrict__ partials, int N)
{
    __shared__ int wsum[4];
    int b = blockIdx.x;
    int tid = threadIdx.x, lane = tid & 63, w = tid >> 6;
    int i0 = b * 1024 + tid * 4;
    int v0 = (i0     < N) ? cnt[i0]     : 0;
    int v1 = (i0 + 1 < N) ? cnt[i0 + 1] : 0;
    int v2 = (i0 + 2 < N) ? cnt[i0 + 2] : 0;
    int v3 = (i0 + 3 < N) ? cnt[i0 + 3] : 0;
    int tsum = v0 + v1 + v2 + v3;
    int s = tsum;
#pragma unroll
    for (int off = 1; off < 64; off <<= 1) {
        int u = __shfl_up(s, off, 64);
        if (lane >= off) s += u;
    }
    if (lane == 63) wsum[w] = s;
    __syncthreads();
    int woff = 0;
    for (int k = 0; k < w; k++) woff += wsum[k];
    int ex = woff + s - tsum;
    if (i0     < N) rowstart[i0]     = ex;
    if (i0 + 1 < N) rowstart[i0 + 1] = ex + v0;
    if (i0 + 2 < N) rowstart[i0 + 2] = ex + v0 + v1;
    if (i0 + 3 < N) rowstart[i0 + 3] = ex + v0 + v1 + v2;
    if (tid == 255) partials[b] = woff + s;
}

__global__ __launch_bounds__(64) void scan2_kernel(
    int* __restrict__ partials, int* __restrict__ rowstart, int nblk, int N)
{
    int lane = threadIdx.x;
    int carry = 0;
    for (int base = 0; base < nblk; base += 64) {
        int i = base + lane;
        int v = (i < nblk) ? partials[i] : 0;
        int s = v;
#pragma unroll
        for (int off = 1; off < 64; off <<= 1) {
            int u = __shfl_up(s, off, 64);
            if (lane >= off) s += u;
        }
        if (i < nblk) partials[i] = carry + s - v;
        carry += __shfl(s, 63, 64);
    }
    if (lane == 0) rowstart[N] = carry;
}

__global__ __launch_bounds__(256) void scan3_kernel(
    int* __restrict__ rowstart, const int* __restrict__ partials, int N)
{
    int i = blockIdx.x * blockDim.x + threadIdx.x;
    if (i < N) rowstart[i] += partials[i >> 10];
}

__global__ __launch_bounds__(256) void scatter_kernel(
    const int* __restrict__ src, const int* __restrict__ dst,
    const float* __restrict__ ea, const float* __restrict__ qy,
    const int* __restrict__ rowstart, int* __restrict__ cursor,
    uint4* __restrict__ epack, int E)
{
    int e = blockIdx.x * blockDim.x + threadIdx.x;
    if (e >= E) return;
    int d = dst[e];
    int pos = atomicAdd(&cursor[d], 1);
    uint4 pk;
    pk.x = (uint)e;
    pk.y = (uint)src[e];
    pk.z = __float_as_uint(ea[e]);
    pk.w = __float_as_uint(qy[e]);
    epack[rowstart[d] + pos] = pk;
}

// ---------------- layer 1 (scalar channel), pull over CSR, unroll 2 ----------------
__global__ __launch_bounds__(256) void edge1_kernel(
    const float* __restrict__ x, const uint4* __restrict__ epack,
    const int* __restrict__ rowstart, const float* __restrict__ scal,
    float* __restrict__ agg1, int N)
{
    int v = blockIdx.x * blockDim.x + threadIdx.x;
    if (v >= N) return;
    float s0 = scal[0], s1 = scal[1], s2 = scal[2];
    int beg = rowstart[v], end = rowstart[v + 1];
    float m = 0.0f;
    int i = beg;
    for (; i + 2 <= end; i += 2) {
        uint4 pk0 = epack[i];
        uint4 pk1 = epack[i + 1];
        float x0 = x[(int)pk0.y];
        float x1 = x[(int)pk1.y];
        m += fmaxf(x0 + fmaf(__uint_as_float(pk0.z), s0, fmaf(__uint_as_float(pk0.w), s1, s2)), 0.0f);
        m += fmaxf(x1 + fmaf(__uint_as_float(pk1.z), s0, fmaf(__uint_as_float(pk1.w), s1, s2)), 0.0f);
    }
    if (i < end) {
        uint4 pk = epack[i];
        m += fmaxf(x[(int)pk.y] + fmaf(__uint_as_float(pk.z), s0, fmaf(__uint_as_float(pk.w), s1, s2)), 0.0f);
    }
    agg1[v] = m;
}

// h1 = (x+agg1)*Wn1 + bn1 + temb -> bf16 shadow only
__global__ __launch_bounds__(256) void node1_kernel(
    const float* __restrict__ x, const float* __restrict__ agg1,
    const float* __restrict__ Wn1, const float* __restrict__ bn1,
    const float* __restrict__ temb, uint* __restrict__ h16u, int N)
{
    int i = blockIdx.x * blockDim.x + threadIdx.x;  // N*64 threads
    int n = i >> 6, j2 = (i & 63) * 2;
    if (n >= N) return;
    float v = x[n] + agg1[n];
    float h0 = fmaf(v, Wn1[j2],     bn1[j2]     + temb[j2]);
    float h1 = fmaf(v, Wn1[j2 + 1], bn1[j2 + 1] + temb[j2 + 1]);
    h16u[(size_t)n * 64 + (j2 >> 1)] = packbf(h0, h1);
}

// ------------ layers 2/3: pull aggregation (bf16 h gather), unroll 8, bf16 agg out --
__global__ __launch_bounds__(256) void aggL_kernel(
    const uint* __restrict__ h16u, const uint4* __restrict__ epack,
    const int* __restrict__ rowstart,
    const float* __restrict__ P, const float* __restrict__ Q,
    const float* __restrict__ R, uint* __restrict__ agg16u, int N)
{
    int v = blockIdx.x * 4 + (threadIdx.x >> 6);
    int lane = threadIdx.x & 63;
    if (v >= N) return;
    int c = lane * 2;
    float2 Pv = *(const float2*)(P + c);
    float2 Qv = *(const float2*)(Q + c);
    float2 Rv = *(const float2*)(R + c);
    int beg = rowstart[v], end = rowstart[v + 1];
    float accx = 0.0f, accy = 0.0f;
    int i = beg;
    for (; i + 8 <= end; i += 8) {
        uint4 pk[8];
        uint hp[8];
#pragma unroll
        for (int j = 0; j < 8; j++) pk[j] = epack[i + j];
#pragma unroll
        for (int j = 0; j < 8; j++) hp[j] = h16u[(size_t)pk[j].y * 64 + lane];
#pragma unroll
        for (int j = 0; j < 8; j++) {
            float a = __uint_as_float(pk[j].z), b = __uint_as_float(pk[j].w);
            accx += fmaxf(bf2f_lo(hp[j]) + fmaf(a, Pv.x, fmaf(b, Qv.x, Rv.x)), 0.0f);
            accy += fmaxf(bf2f_hi(hp[j]) + fmaf(a, Pv.y, fmaf(b, Qv.y, Rv.y)), 0.0f);
        }
    }
    for (; i + 2 <= end; i += 2) {
        uint4 pk0 = epack[i];
        uint4 pk1 = epack[i + 1];
        uint hp0 = h16u[(size_t)pk0.y * 64 + lane];
        uint hp1 = h16u[(size_t)pk1.y * 64 + lane];
        float a0 = __uint_as_float(pk0.z), b0 = __uint_as_float(pk0.w);
        float a1 = __uint_as_float(pk1.z), b1 = __uint_as_float(pk1.w);
        accx += fmaxf(bf2f_lo(hp0) + fmaf(a0, Pv.x, fmaf(b0, Qv.x, Rv.x)), 0.0f);
        accy += fmaxf(bf2f_hi(hp0) + fmaf(a0, Pv.y, fmaf(b0, Qv.y, Rv.y)), 0.0f);
        accx += fmaxf(bf2f_lo(hp1) + fmaf(a1, Pv.x, fmaf(b1, Qv.x, Rv.x)), 0.0f);
        accy += fmaxf(bf2f_hi(hp1) + fmaf(a1, Pv.y, fmaf(b1, Qv.y, Rv.y)), 0.0f);
    }
    if (i < end) {
        uint4 pk = epack[i];
        float a = __uint_as_float(pk.z), b = __uint_as_float(pk.w);
        uint hp = h16u[(size_t)pk.y * 64 + lane];
        accx += fmaxf(bf2f_lo(hp) + fmaf(a, Pv.x, fmaf(b, Qv.x, Rv.x)), 0.0f);
        accy += fmaxf(bf2f_hi(hp) + fmaf(a, Pv.y, fmaf(b, Qv.y, Rv.y)), 0.0f);
    }
    agg16u[(size_t)v * 64 + lane] = packbf(accx, accy);
}

// ----- layer 2 node update via MFMA: 64 nodes/block, wave = 16-row tile x 8 col-tiles
__global__ __launch_bounds__(256) void nodeL_kernel(
    const uint* __restrict__ agg16u, const uint* __restrict__ Wn2t16u,
    const float* __restrict__ bn, const float* __restrict__ temb,
    uint* __restrict__ h16u, int N)
{
    __shared__ uint vs16[64][68];   // (h+agg) bf16 pairs, 17.4 KB
    int nb = blockIdx.x * 64;
    int tid = threadIdx.x;
    for (int idx = tid; idx < 64 * 32; idx += 256) {   // uint2 per idx
        int n = idx >> 5, u2 = (idx & 31) * 2;
        uint2 pk = make_uint2(0, 0);
        if (nb + n < N) {
            uint2 hp = *(const uint2*)(h16u + (size_t)(nb + n) * 64 + u2);
            uint2 gp = *(const uint2*)(agg16u + (size_t)(nb + n) * 64 + u2);
            pk.x = packbf(bf2f_lo(hp.x) + bf2f_lo(gp.x), bf2f_hi(hp.x) + bf2f_hi(gp.x));
            pk.y = packbf(bf2f_lo(hp.y) + bf2f_lo(gp.y), bf2f_hi(hp.y) + bf2f_hi(gp.y));
        }
        *(uint2*)(&vs16[n][u2]) = pk;
    }
    __syncthreads();
    int wv = tid >> 6, lane = tid & 63, cl = lane & 15, g = lane >> 4;
    int rbase = wv * 16;
    short8 afr[4];
#pragma unroll
    for (int kc = 0; kc < 4; kc++) {
        U4S8 t;
        t.u = *(const uint4*)(&vs16[rbase + cl][kc * 16 + g * 4]);
        afr[kc] = t.s;
    }
#pragma unroll
    for (int tt = 0; tt < 8; tt++) {
        int c = tt * 16 + cl;
        float bias = bn[c] + temb[c];
        f32x4 acc = {bias, bias, bias, bias};
#pragma unroll
        for (int kc = 0; kc < 4; kc++) {
            U4S8 t;
            t.u = *(const uint4*)(Wn2t16u + (size_t)c * 64 + kc * 16 + g * 4);
            acc = __builtin_amdgcn_mfma_f32_16x16x32_bf16(afr[kc], t.s, acc, 0, 0, 0);
        }
#pragma unroll
        for (int r = 0; r < 4; r++) {
            int n = nb + rbase + g * 4 + r;
            float val = acc[r];
            float nbr = __shfl_down(val, 1, 64);
            if (n < N && (cl & 1) == 0)
                h16u[(size_t)n * 64 + (c >> 1)] = packbf(val, nbr);
        }
    }
}

// ------- fused layer-3 node update + decode A/B precompute, all-MFMA -------
__global__ __launch_bounds__(256) void node3_decode_kernel(
    const uint* __restrict__ h16u, const uint* __restrict__ agg16u,
    const uint* __restrict__ Wn3t16u, const float* __restrict__ bn3,
    const float* __restrict__ temb, const uint* __restrict__ Wt16u,
    const float* __restrict__ Wd1, const float* __restrict__ bd1,
    ushort* __restrict__ A16s, ushort* __restrict__ B16s, int N)
{
    __shared__ uint vs16[16][68];    // (h+agg) bf16 pairs, 4.35 KB
    __shared__ float hs3[16][132];   // h3 f32, 8.45 KB
    int nb = blockIdx.x * 16;
    int tid = threadIdx.x;
    for (int idx = tid; idx < 16 * 32; idx += 256) {   // uint2 per idx
        int n = idx >> 5, u2 = (idx & 31) * 2;
        uint2 pk = make_uint2(0, 0);
        if (nb + n < N) {
            uint2 hp = *(const uint2*)(h16u + (size_t)(nb + n) * 64 + u2);
            uint2 gp = *(const uint2*)(agg16u + (size_t)(nb + n) * 64 + u2);
            pk.x = packbf(bf2f_lo(hp.x) + bf2f_lo(gp.x), bf2f_hi(hp.x) + bf2f_hi(gp.x));
            pk.y = packbf(bf2f_lo(hp.y) + bf2f_lo(gp.y), bf2f_hi(hp.y) + bf2f_hi(gp.y));
        }
        *(uint2*)(&vs16[n][u2]) = pk;
    }
    __syncthreads();
    int wv = tid >> 6, lane = tid & 63, cl = lane & 15, g = lane >> 4;
    // phase 1 (MFMA): h3(16x128) = vs(16x128) @ Wn3(128x128) + bn3 + temb -> hs3 f32
    {
        short8 afr[4];
#pragma unroll
        for (int kc = 0; kc < 4; kc++) {
            U4S8 t;
            t.u = *(const uint4*)(&vs16[cl][kc * 16 + g * 4]);
            afr[kc] = t.s;
        }
#pragma unroll
        for (int tt = 0; tt < 2; tt++) {
            int c = wv * 32 + tt * 16 + cl;
            float bias = bn3[c] + temb[c];
            f32x4 acc = {bias, bias, bias, bias};
#pragma unroll
            for (int kc = 0; kc < 4; kc++) {
                U4S8 t;
                t.u = *(const uint4*)(Wn3t16u + (size_t)c * 64 + kc * 16 + g * 4);
                acc = __builtin_amdgcn_mfma_f32_16x16x32_bf16(afr[kc], t.s, acc, 0, 0, 0);
            }
#pragma unroll
            for (int r = 0; r < 4; r++) hs3[g * 4 + r][c] = acc[r];
        }
    }
    __syncthreads();
    // phase 2 (MFMA): [A|B](16x512) = h3 @ Wt16 ; pack A-frags from hs3 f32
    {
        short8 afr[4];
#pragma unroll
        for (int kc = 0; kc < 4; kc++) {
            float4 lo = *(const float4*)(&hs3[cl][kc * 32 + g * 8]);
            float4 hi = *(const float4*)(&hs3[cl][kc * 32 + g * 8 + 4]);
            U4S8 t;
            t.u.x = packbf(lo.x, lo.y);
            t.u.y = packbf(lo.z, lo.w);
            t.u.z = packbf(hi.x, hi.y);
            t.u.w = packbf(hi.z, hi.w);
            afr[kc] = t.s;
        }
#pragma unroll
        for (int tt = 0; tt < 8; tt++) {
            int tile = wv * 8 + tt;
            int c = tile * 16 + cl;            // combined col 0..511
            float bias = (tile < 16) ? bd1[c] : 0.0f;
            f32x4 acc = {bias, bias, bias, bias};
#pragma unroll
            for (int kc = 0; kc < 4; kc++) {
                U4S8 t;
                t.u = *(const uint4*)(Wt16u + (size_t)c * 64 + kc * 16 + g * 4);
                acc = __builtin_amdgcn_mfma_f32_16x16x32_bf16(afr[kc], t.s, acc, 0, 0, 0);
            }
            ushort* OUT = (tile < 16) ? A16s : B16s;
            int oc = (tile < 16) ? c : (c - 256);
#pragma unroll
            for (int r = 0; r < 4; r++) {
                int n = nb + g * 4 + r;
                if (n < N) OUT[(size_t)n * 264 + oc] = f2bf(acc[r]);
            }
        }
    }
    // tail: o = 256 column, 4 lanes per node + shfl reduce
    if (tid < 64) {
        int n = tid >> 2, j = tid & 3;
        float sA = 0.f, sB = 0.f;
        for (int k = j * 32; k < j * 32 + 32; k++) {
            float hv = hs3[n][k];
            sA = fmaf(hv, Wd1[k * 257 + 256], sA);
            sB = fmaf(hv, Wd1[(128 + k) * 257 + 256], sB);
        }
        sA += __shfl_xor(sA, 1, 64);
        sA += __shfl_xor(sA, 2, 64);
        sB += __shfl_xor(sB, 1, 64);
        sB += __shfl_xor(sB, 2, 64);
        if (j == 0 && nb + n < N) {
            A16s[(size_t)(nb + n) * 264 + 256] = f2bf(sA + bd1[256]);
            B16s[(size_t)(nb + n) * 264 + 256] = f2bf(sB);
        }
    }
}

// ---- decode edges, dst-grouped: wave per node, bf16 A gather, B in regs, unroll 4 ----
__global__ __launch_bounds__(256) void decodeE_kernel(
    const uint* __restrict__ A16u, const uint* __restrict__ B16u,
    const uint4* __restrict__ epack, const int* __restrict__ rowstart,
    const float* __restrict__ Wd1, const float* __restrict__ Wd2,
    const float* __restrict__ bd2, float* __restrict__ out, int N)
{
    int v = blockIdx.x * 4 + (threadIdx.x >> 6);
    int lane = threadIdx.x & 63;
    if (v >= N) return;
    const float* w256 = Wd1 + 256 * 257;
    float4 w2v = *(const float4*)(w256 + lane * 4);
    float4 wdv = *(const float4*)(Wd2 + lane * 4);
    const uint* Br = B16u + (size_t)v * AB_U;
    uint2 bp = *(const uint2*)(Br + lane * 2);
    float Bv0 = bf2f_lo(bp.x), Bv1 = bf2f_hi(bp.x);
    float Bv2 = bf2f_lo(bp.y), Bv3 = bf2f_hi(bp.y);
    float w2_l = w256[256], wd_l = Wd2[256], bd = bd2[0];
    float B_l = bf2f_lo(Br[128]);
    int beg = rowstart[v], end = rowstart[v + 1];
    int i = beg;
    for (; i + 4 <= end; i += 4) {
        uint4 pk[4];
        uint2 ap[4];
#pragma unroll
        for (int j = 0; j < 4; j++) pk[j] = epack[i + j];
#pragma unroll
        for (int j = 0; j < 4; j++)
            ap[j] = *(const uint2*)(A16u + (size_t)pk[j].y * AB_U + lane * 2);
        float tl[4];
        if (lane == 0) {
#pragma unroll
            for (int j = 0; j < 4; j++)
                tl[j] = bf2f_lo(A16u[(size_t)pk[j].y * AB_U + 128]);
        }
        float acc[4];
#pragma unroll
        for (int j = 0; j < 4; j++) {
            float q = __uint_as_float(pk[j].w);
            float y0 = bf2f_lo(ap[j].x) + fmaf(q, w2v.x, Bv0);
            float y1 = bf2f_hi(ap[j].x) + fmaf(q, w2v.y, Bv1);
            float y2 = bf2f_lo(ap[j].y) + fmaf(q, w2v.z, Bv2);
            float y3 = bf2f_hi(ap[j].y) + fmaf(q, w2v.w, Bv3);
            acc[j] = fmaxf(y0, 0.f) * wdv.x + fmaxf(y1, 0.f) * wdv.y
                   + fmaxf(y2, 0.f) * wdv.z + fmaxf(y3, 0.f) * wdv.w;
            if (lane == 0)
                acc[j] = fmaf(fmaxf(tl[j] + fmaf(q, w2_l, B_l), 0.f), wd_l, acc[j]);
        }
#pragma unroll
        for (int off = 32; off > 0; off >>= 1) {
#pragma unroll
            for (int j = 0; j < 4; j++) acc[j] += __shfl_xor(acc[j], off, 64);
        }
        if (lane == 0) {
#pragma unroll
            for (int j = 0; j < 4; j++) out[(int)pk[j].x] = acc[j] + bd;
        }
    }
    for (; i < end; i++) {
        uint4 pk = epack[i];
        float q = __uint_as_float(pk.w);
        const uint* Ar = A16u + (size_t)pk.y * AB_U;
        uint2 ap = *(const uint2*)(Ar + lane * 2);
        float y0 = bf2f_lo(ap.x) + fmaf(q, w2v.x, Bv0);
        float y1 = bf2f_hi(ap.x) + fmaf(q, w2v.y, Bv1);
        float y2 = bf2f_lo(ap.y) + fmaf(q, w2v.z, Bv2);
        float y3 = bf2f_hi(ap.y) + fmaf(q, w2v.w, Bv3);
        float acc = fmaxf(y0, 0.f) * wdv.x + fmaxf(y1, 0.f) * wdv.y
                  + fmaxf(y2, 0.f) * wdv.z + fmaxf(y3, 0.f) * wdv.w;
        if (lane == 0) {
            float yl = bf2f_lo(Ar[128]) + fmaf(q, w2_l, B_l);
            acc = fmaf(fmaxf(yl, 0.f), wd_l, acc);
        }
#pragma unroll
        for (int off = 32; off > 0; off >>= 1) acc += __shfl_xor(acc, off, 64);
        if (lane == 0) out[(int)pk.x] = acc + bd;
    }
}

extern "C" void kernel_launch(void* const* d_in, const int* in_sizes, int n_in,
                              void* d_out, int out_size, void* d_ws, size_t ws_size,
                              hipStream_t stream) {
    (void)n_in; (void)out_size; (void)ws_size;
    const float* x   = (const float*)d_in[0];
    const float* ea  = (const float*)d_in[1];
    const float* qy  = (const float*)d_in[2];
    const int*   adj = (const int*)d_in[3];
    const float* t   = (const float*)d_in[4];
    // d_in[5]=num_steps (unused), d_in[6]=batch (unused)
    const float* We  = (const float*)d_in[7];
    const float* be  = (const float*)d_in[8];
    const float* Wo  = (const float*)d_in[9];
    const float* bo  = (const float*)d_in[10];
    const float* Wl1 = (const float*)d_in[11];
    const float* bl1 = (const float*)d_in[12];
    const float* Wn1 = (const float*)d_in[13];
    const float* bn1 = (const float*)d_in[14];
    const float* Wl2 = (const float*)d_in[15];
    const float* bl2 = (const float*)d_in[16];
    const float* Wn2 = (const float*)d_in[17];
    const float* bn2 = (const float*)d_in[18];
    const float* Wl3 = (const float*)d_in[19];
    const float* bl3 = (const float*)d_in[20];
    const float* Wn3 = (const float*)d_in[21];
    const float* bn3 = (const float*)d_in[22];
    const float* Wt1 = (const float*)d_in[23];
    const float* bt1 = (const float*)d_in[24];
    const float* Wt2 = (const float*)d_in[25];
    const float* bt2 = (const float*)d_in[26];
    const float* Wd1 = (const float*)d_in[27];
    const float* bd1 = (const float*)d_in[28];
    const float* Wd2 = (const float*)d_in[29];
    const float* bd2 = (const float*)d_in[30];
    float* out = (float*)d_out;

    int N = in_sizes[0];
    int E = in_sizes[3] / 2;
    const int* src = adj;
    const int* dst = adj + E;

    float* w    = (float*)d_ws;
    float* temb = w;            // wsmall block (1024 floats)
    float* P2   = w + 128;
    float* Q2   = w + 256;
    float* R2   = w + 384;
    float* P3   = w + 512;
    float* Q3   = w + 640;
    float* R3   = w + 768;
    float* scal = w + 896;
    float* agg1 = w + 1024;                          // N f32 (layer-1 scalar agg)
    uint*  h16u   = (uint*)(agg1 + N);               // N*64 uints (bf16 pairs)
    uint*  agg16u = h16u + (size_t)N * 64;           // N*64 uints (bf16 pairs)
    uint*  A16u   = agg16u + (size_t)N * 64;         // N*AB_U uints
    uint*  B16u   = A16u + (size_t)N * AB_U;         // N*AB_U uints
    int* rowstart = (int*)(B16u + (size_t)N * AB_U); // N+1
    int* cursor   = rowstart + (N + 1);              // N
    int* partials = cursor + N;
    int nblk = (N + 1023) / 1024;
    char* pcur = (char*)(partials + nblk + 1);
    pcur = (char*)(((uintptr_t)pcur + 15) & ~(uintptr_t)15);
    uint4* epack = (uint4*)pcur;                     // E * 16B
    uint* Wt16u   = (uint*)(epack + E);              // 512*64 uints (bf16 Wd1^T)
    uint* Wn2t16u = Wt16u + 512 * 64;                // 128*64 uints
    uint* Wn3t16u = Wn2t16u + 128 * 64;              // 128*64 uints

    // ---- CSR build (by dst) ----
    hipMemsetAsync(cursor, 0, (size_t)N * sizeof(int), stream);
    hist_kernel<<<(E + 255) / 256, 256, 0, stream>>>(dst, cursor, E);
    scan1_kernel<<<nblk, 256, 0, stream>>>(cursor, rowstart, partials, N);
    scan2_kernel<<<1, 64, 0, stream>>>(partials, rowstart, nblk, N);
    scan3_kernel<<<(N + 255) / 256, 256, 0, stream>>>(rowstart, partials, N);
    hipMemsetAsync(cursor, 0, (size_t)N * sizeof(int), stream);
    scatter_kernel<<<(E + 255) / 256, 256, 0, stream>>>(src, dst, ea, qy, rowstart, cursor, epack, E);

    wt16_kernel<<<512, 64, 0, stream>>>(Wd1, Wt16u);
    wnt16_kernel<<<128, 64, 0, stream>>>(Wn2, Wn2t16u);
    wnt16_kernel<<<128, 64, 0, stream>>>(Wn3, Wn3t16u);
    precompute_kernel<<<1, 256, 0, stream>>>(t, We, be, Wo, bo, Wl1, bl1,
                                             Wl2, bl2, Wl3, bl3,
                                             Wt1, bt1, Wt2, bt2, w);
    // layer 1
    edge1_kernel<<<(N + 255) / 256, 256, 0, stream>>>(x, epack, rowstart, scal, agg1, N);
    node1_kernel<<<(N * 64 + 255) / 256, 256, 0, stream>>>(x, agg1, Wn1, bn1, temb, h16u, N);
    // layer 2
    aggL_kernel<<<(N + 3) / 4, 256, 0, stream>>>(h16u, epack, rowstart, P2, Q2, R2, agg16u, N);
    nodeL_kernel<<<(N + 63) / 64, 256, 0, stream>>>(agg16u, Wn2t16u, bn2, temb, h16u, N);
    // layer 3 (node update fused with decode A/B precompute, all-MFMA)
    aggL_kernel<<<(N + 3) / 4, 256, 0, stream>>>(h16u, epack, rowstart, P3, Q3, R3, agg16u, N);
    node3_decode_kernel<<<(N + 15) / 16, 256, 0, stream>>>(h16u, agg16u, Wn3t16u, bn3, temb,
                                                           Wt16u, Wd1, bd1,
                                                           (ushort*)A16u, (ushort*)B16u, N);
    // decode edges
    decodeE_kernel<<<(N + 3) / 4, 256, 0, stream>>>(A16u, B16u, epack, rowstart, Wd1, Wd2, bd2, out, N);
}